// Round 3
// baseline (3942.432 us; speedup 1.0000x reference)
//
#include <hip/hip_runtime.h>
#include <hip/hip_cooperative_groups.h>

namespace cg = cooperative_groups;

#define BATCH 32
#define PIX   3072
#define NEU   4096
#define STEPS 99           // reference runs NUM_STEPS-1 = 99 update iterations
#define ETA   (0.001f / 0.03f)

typedef __bf16 bf16x8 __attribute__((ext_vector_type(8)));
typedef float  f32x4  __attribute__((ext_vector_type(4)));

__device__ __forceinline__ float softt(float u, float lam) {
    return u > lam ? u - lam : (u < -lam ? u + lam : 0.0f);
}

// fp32 -> bf16 round-to-nearest-even
__device__ __forceinline__ unsigned short f2b(float f) {
    unsigned int u = __builtin_bit_cast(unsigned int, f);
    u = (u + 0x7FFFu + ((u >> 16) & 1u)) >> 16;
    return (unsigned short)u;
}

__device__ __forceinline__ bf16x8 ldfrag_g(const unsigned short* p) {
    uint4 v = *(const uint4*)p;
    return __builtin_bit_cast(bf16x8, v);
}

// ---------------------------------------------------------------------------
// φ (fp32 [PIX][NEU]) -> φT (bf16 [NEU][PIX]).  64x64 tiles via LDS.
// grid (NEU/64, PIX/64), block 256
__global__ void transp(const float* __restrict__ phi, unsigned short* __restrict__ phiT) {
    __shared__ float t[64][65];
    const int n0 = blockIdx.x * 64, p0 = blockIdx.y * 64;
    const int tid = threadIdx.x;
    #pragma unroll
    for (int pass = 0; pass < 4; ++pass) {
        const int r  = pass * 16 + (tid >> 4);
        const int c4 = (tid & 15) * 4;
        float4 v = *(const float4*)(phi + (size_t)(p0 + r) * NEU + n0 + c4);
        t[r][c4 + 0] = v.x; t[r][c4 + 1] = v.y; t[r][c4 + 2] = v.z; t[r][c4 + 3] = v.w;
    }
    __syncthreads();
    #pragma unroll
    for (int pass = 0; pass < 2; ++pass) {
        const int cp = pass * 32 + (tid >> 3);   // n-column -> φT row
        const int p8 = (tid & 7) * 8;            // 8 consecutive p
        unsigned int w0 = (unsigned int)f2b(t[p8 + 0][cp]) | ((unsigned int)f2b(t[p8 + 1][cp]) << 16);
        unsigned int w1 = (unsigned int)f2b(t[p8 + 2][cp]) | ((unsigned int)f2b(t[p8 + 3][cp]) << 16);
        unsigned int w2 = (unsigned int)f2b(t[p8 + 4][cp]) | ((unsigned int)f2b(t[p8 + 5][cp]) << 16);
        unsigned int w3 = (unsigned int)f2b(t[p8 + 6][cp]) | ((unsigned int)f2b(t[p8 + 7][cp]) << 16);
        uint4 o = make_uint4(w0, w1, w2, w3);
        *(uint4*)(phiT + (size_t)(n0 + cp) * PIX + p0 + p8) = o;
    }
}

// ---------------------------------------------------------------------------
// G = φᵀφ (symmetric, bf16). Upper-triangle blocks only; mirror-store.
// grid (32,32) with lower-half early exit; block 256 (4 waves, 128x128 tile).
// LDS row stride padded 32->40 elem (80 B = 20 banks) to break conflicts.
__global__ void gemm_G(const unsigned short* __restrict__ phiT, unsigned short* __restrict__ G) {
    if (blockIdx.y > blockIdx.x) return;       // keep m0 <= n0
    __shared__ __align__(16) unsigned short lds[2][128 * 40];
    const int m0 = blockIdx.y * 128, n0 = blockIdx.x * 128;
    const int tid  = threadIdx.x;
    const int lane = tid & 63, w = tid >> 6;
    const int wm = (w & 1) * 64, wn = (w >> 1) * 64;
    const int q8 = (lane >> 4) * 8, l15 = lane & 15;
    f32x4 acc[4][4] = {};
    for (int k0 = 0; k0 < PIX; k0 += 32) {
        __syncthreads();
        #pragma unroll
        for (int it = 0; it < 2; ++it) {
            const int id = tid + 256 * it;       // 0..511
            const int row = id >> 2, q = id & 3;
            uint4 va = *(const uint4*)(phiT + (size_t)(m0 + row) * PIX + k0 + q * 8);
            *(uint4*)(&lds[0][row * 40 + q * 8]) = va;
            uint4 vb = *(const uint4*)(phiT + (size_t)(n0 + row) * PIX + k0 + q * 8);
            *(uint4*)(&lds[1][row * 40 + q * 8]) = vb;
        }
        __syncthreads();
        bf16x8 af[4], bfr[4];
        #pragma unroll
        for (int i = 0; i < 4; ++i) {
            af[i]  = *(const bf16x8*)(&lds[0][(wm + i * 16 + l15) * 40 + q8]);
            bfr[i] = *(const bf16x8*)(&lds[1][(wn + i * 16 + l15) * 40 + q8]);
        }
        #pragma unroll
        for (int i = 0; i < 4; ++i)
            #pragma unroll
            for (int j = 0; j < 4; ++j)
                acc[i][j] = __builtin_amdgcn_mfma_f32_16x16x32_bf16(af[i], bfr[j], acc[i][j], 0, 0, 0);
    }
    const int q = lane >> 4;
    const bool offdiag = (blockIdx.y != blockIdx.x);
    #pragma unroll
    for (int i = 0; i < 4; ++i)
        #pragma unroll
        for (int j = 0; j < 4; ++j) {
            unsigned short pk[4];
            #pragma unroll
            for (int r = 0; r < 4; ++r) {
                const int gm = m0 + wm + i * 16 + q * 4 + r;
                const int gn = n0 + wn + j * 16 + l15;
                const unsigned short v = f2b(acc[i][j][r]);
                G[(size_t)gm * NEU + gn] = v;   // coalesced across l15
                pk[r] = v;
            }
            if (offdiag) {
                // mirror: G[gn][gm..gm+3] -- 8 B packed store per lane
                const int gm0 = m0 + wm + i * 16 + q * 4;
                const int gn  = n0 + wn + j * 16 + l15;
                *(ushort4*)(G + (size_t)gn * NEU + gm0) = make_ushort4(pk[0], pk[1], pk[2], pk[3]);
            }
        }
}

// ---------------------------------------------------------------------------
// b = x @ phi  (B[k][n] = phiT[n][k] rows), zero-init of a-ping buffer.
// grid 256 (16-col strips), block 512 (8 waves, 8-way split-K over PIX)
__global__ void lca_binit(const float* __restrict__ x, const unsigned short* __restrict__ phiT,
                          float* __restrict__ b, unsigned short* __restrict__ ab0) {
    __shared__ float red[8 * 512];
    const int tid = threadIdx.x;
    const int lane = tid & 63, w = tid >> 6;
    const int n0 = blockIdx.x * 16;
    const int kbase = w * (PIX / 8);             // 384
    const int q8 = (lane >> 4) * 8, l15 = lane & 15;
    f32x4 acc[2] = {};
    const unsigned short* Brow = phiT + (size_t)(n0 + l15) * PIX + kbase + q8;
    const float* X0 = x + (size_t)l15 * PIX + kbase + q8;
    const float* X1 = x + (size_t)(16 + l15) * PIX + kbase + q8;
    #pragma unroll 4
    for (int kk = 0; kk < PIX / 8; kk += 32) {
        bf16x8 bg = ldfrag_g(Brow + kk);
        float4 xa0 = *(const float4*)(X0 + kk), xb0 = *(const float4*)(X0 + kk + 4);
        float4 xa1 = *(const float4*)(X1 + kk), xb1 = *(const float4*)(X1 + kk + 4);
        bf16x8 a0, a1;
        a0[0]=(__bf16)xa0.x; a0[1]=(__bf16)xa0.y; a0[2]=(__bf16)xa0.z; a0[3]=(__bf16)xa0.w;
        a0[4]=(__bf16)xb0.x; a0[5]=(__bf16)xb0.y; a0[6]=(__bf16)xb0.z; a0[7]=(__bf16)xb0.w;
        a1[0]=(__bf16)xa1.x; a1[1]=(__bf16)xa1.y; a1[2]=(__bf16)xa1.z; a1[3]=(__bf16)xa1.w;
        a1[4]=(__bf16)xb1.x; a1[5]=(__bf16)xb1.y; a1[6]=(__bf16)xb1.z; a1[7]=(__bf16)xb1.w;
        acc[0] = __builtin_amdgcn_mfma_f32_16x16x32_bf16(a0, bg, acc[0], 0, 0, 0);
        acc[1] = __builtin_amdgcn_mfma_f32_16x16x32_bf16(a1, bg, acc[1], 0, 0, 0);
    }
    const int q = lane >> 4;
    #pragma unroll
    for (int mt = 0; mt < 2; ++mt)
        #pragma unroll
        for (int r = 0; r < 4; ++r)
            red[w * 512 + (mt * 16 + q * 4 + r) * 16 + l15] = acc[mt][r];
    __syncthreads();
    float s = 0.f;
    #pragma unroll
    for (int w8 = 0; w8 < 8; ++w8) s += red[w8 * 512 + tid];
    const int m = tid >> 4, n = n0 + (tid & 15);
    const size_t idx = (size_t)m * NEU + n;
    b[idx] = s; ab0[idx] = 0;
}

// ---------------------------------------------------------------------------
// Persistent cooperative kernel: all 99 steps, one grid sync each.
// Block bx owns columns [bx*16, bx*16+16). G fragments live in REGISTERS
// (loaded once); u/b/a are thread-private registers; a ping-pongs in global.
__global__ void __launch_bounds__(512, 2)
lca_persist(const unsigned short* __restrict__ G, const float* __restrict__ b,
            unsigned short* __restrict__ ab0, unsigned short* __restrict__ ab1,
            float* __restrict__ aout, const float* __restrict__ lamp) {
    cg::grid_group grid = cg::this_grid();
    __shared__ float red[8 * 512];
    const int tid = threadIdx.x;
    const int lane = tid & 63, w = tid >> 6;
    const int n0 = blockIdx.x * 16;
    const int kbase = w * (NEU / 8);             // 512
    const int q8 = (lane >> 4) * 8, l15 = lane & 15;
    const int q = lane >> 4;

    // G fragments for this wave's k-range: constant across all steps.
    bf16x8 gf[16];
    {
        const unsigned short* Grow = G + (size_t)(n0 + l15) * NEU + kbase + q8;
        #pragma unroll
        for (int it = 0; it < 16; ++it)
            gf[it] = ldfrag_g(Grow + it * 32);
    }

    // Thread-private state: thread tid owns (m = tid>>4, n = n0 + (tid&15))
    const int m = tid >> 4;
    const size_t idx = (size_t)m * NEU + n0 + (tid & 15);
    float bv = b[idx];
    float uv = 0.f, av = 0.f;
    const float lam = lamp[0];

    for (int step = 0; step < STEPS; ++step) {
        const unsigned short* rd = (step & 1) ? ab1 : ab0;
        unsigned short*       wr = (step & 1) ? ab0 : ab1;
        const unsigned short* A0 = rd + (size_t)l15 * NEU + kbase + q8;
        const unsigned short* A1 = rd + (size_t)(16 + l15) * NEU + kbase + q8;
        f32x4 acc0 = {}, acc1 = {};
        #pragma unroll
        for (int it = 0; it < 16; ++it) {
            bf16x8 a0 = ldfrag_g(A0 + it * 32);
            bf16x8 a1 = ldfrag_g(A1 + it * 32);
            acc0 = __builtin_amdgcn_mfma_f32_16x16x32_bf16(a0, gf[it], acc0, 0, 0, 0);
            acc1 = __builtin_amdgcn_mfma_f32_16x16x32_bf16(a1, gf[it], acc1, 0, 0, 0);
        }
        #pragma unroll
        for (int r = 0; r < 4; ++r) {
            red[w * 512 + (q * 4 + r) * 16 + l15]        = acc0[r];
            red[w * 512 + (16 + q * 4 + r) * 16 + l15]   = acc1[r];
        }
        __syncthreads();
        float s = 0.f;
        #pragma unroll
        for (int w8 = 0; w8 < 8; ++w8) s += red[w8 * 512 + tid];
        const float du = bv - s + av - uv;
        uv = fmaf(ETA, du, uv);
        av = softt(uv, lam);
        wr[idx] = f2b(av);
        if (step == STEPS - 1) aout[idx] = av;
        grid.sync();   // publishes wr, and gates red reuse + rd overwrite
    }
}

// ===========================================================================
// Fallback fp32 path (round-1, known correct) for small ws_size
// ===========================================================================
__global__ void lca_init_f(const float* __restrict__ x, const float* __restrict__ phi,
                           float* __restrict__ b, float* __restrict__ u,
                           float* __restrict__ a) {
    const int n  = blockIdx.x * 64 + (threadIdx.x & 63);
    const int bi = blockIdx.y * 4 + (threadIdx.x >> 6);
    const float* xr = x + bi * PIX;
    float acc = 0.f;
    #pragma unroll 4
    for (int p = 0; p < PIX; ++p) acc = fmaf(xr[p], phi[p * NEU + n], acc);
    const int idx = bi * NEU + n;
    b[idx] = acc; u[idx] = 0.f; a[idx] = 0.f;
}
__global__ void lca_s_f(const float* __restrict__ a, const float* __restrict__ phi,
                        float* __restrict__ s) {
    const int lane = threadIdx.x & 63, w = threadIdx.x >> 6;
    const int bi = blockIdx.y, p0 = (blockIdx.x * 4 + w) * 8;
    const float* ar = a + bi * NEU;
    float acc[8] = {};
    for (int i = 0; i < NEU / 64; ++i) {
        const int n = i * 64 + lane;
        const float av = ar[n];
        #pragma unroll
        for (int j = 0; j < 8; ++j) acc[j] = fmaf(av, phi[(p0 + j) * NEU + n], acc[j]);
    }
    float out = 0.f;
    #pragma unroll
    for (int j = 0; j < 8; ++j) {
        float v = acc[j];
        v += __shfl_xor(v, 1, 64); v += __shfl_xor(v, 2, 64); v += __shfl_xor(v, 4, 64);
        v += __shfl_xor(v, 8, 64); v += __shfl_xor(v, 16, 64); v += __shfl_xor(v, 32, 64);
        if (lane == j) out = v;
    }
    if (lane < 8) s[bi * PIX + p0 + lane] = out;
}
__global__ void lca_t_f(const float* __restrict__ s, const float* __restrict__ phi,
                        const float* __restrict__ b, float* __restrict__ u,
                        float* __restrict__ a, const float* __restrict__ lamp) {
    __shared__ float ls[8 * 256];
    const int n = blockIdx.x * 64 + (threadIdx.x & 63);
    const int slot = threadIdx.x >> 6;
    const int bb = blockIdx.y * 8 + slot;
    float acc = 0.f;
    for (int c = 0; c < PIX; c += 256) {
        __syncthreads();
        for (int e = threadIdx.x; e < 8 * 256; e += 512) {
            const int r = e >> 8, p = e & 255;
            ls[e] = s[(blockIdx.y * 8 + r) * PIX + c + p];
        }
        __syncthreads();
        const float* lrow = ls + slot * 256;
        #pragma unroll 8
        for (int p = 0; p < 256; ++p) acc = fmaf(lrow[p], phi[(c + p) * NEU + n], acc);
    }
    const float lam = lamp[0];
    const int idx = bb * NEU + n;
    const float uo = u[idx];
    const float du = b[idx] - acc + a[idx] - uo;
    const float un = fmaf(ETA, du, uo);
    u[idx] = un; a[idx] = softt(un, lam);
}

// ===========================================================================
extern "C" void kernel_launch(void* const* d_in, const int* in_sizes, int n_in,
                              void* d_out, int out_size, void* d_ws, size_t ws_size,
                              hipStream_t stream) {
    const float* x    = (const float*)d_in[0];
    const float* phi  = (const float*)d_in[1];
    const float* lamp = (const float*)d_in[2];
    float* a = (float*)d_out;
    char* ws = (char*)d_ws;

    const size_t PHIT_OFF = 0;
    const size_t G_OFF    = PHIT_OFF + (size_t)NEU * PIX * 2;       // 24 MB
    const size_t B_OFF    = G_OFF    + (size_t)NEU * NEU * 2;       // +32 MB
    const size_t AB0_OFF  = B_OFF    + (size_t)BATCH * NEU * 4;
    const size_t AB1_OFF  = AB0_OFF  + (size_t)BATCH * NEU * 2;
    const size_t NEED     = AB1_OFF  + (size_t)BATCH * NEU * 2;     // ~57.3 MB

    if (ws_size >= NEED) {
        unsigned short* phiT = (unsigned short*)(ws + PHIT_OFF);
        unsigned short* G    = (unsigned short*)(ws + G_OFF);
        float*          b    = (float*)(ws + B_OFF);
        unsigned short* ab0  = (unsigned short*)(ws + AB0_OFF);
        unsigned short* ab1  = (unsigned short*)(ws + AB1_OFF);

        transp<<<dim3(NEU / 64, PIX / 64), 256, 0, stream>>>(phi, phiT);
        gemm_G<<<dim3(32, 32), 256, 0, stream>>>(phiT, G);
        lca_binit<<<256, 512, 0, stream>>>(x, phiT, b, ab0);

        void* args[6];
        const unsigned short* Gc = G;
        const float* bc = b;
        const float* lc = lamp;
        args[0] = (void*)&Gc;
        args[1] = (void*)&bc;
        args[2] = (void*)&ab0;
        args[3] = (void*)&ab1;
        args[4] = (void*)&a;
        args[5] = (void*)&lc;
        hipLaunchCooperativeKernel((const void*)lca_persist, dim3(256), dim3(512),
                                   args, 0, stream);
    } else {
        float* fws = (float*)d_ws;
        float* b = fws;
        float* u = fws + BATCH * NEU;
        float* s = fws + 2 * BATCH * NEU;
        lca_init_f<<<dim3(64, 8), 256, 0, stream>>>(x, phi, b, u, a);
        for (int it = 0; it < STEPS; ++it) {
            lca_s_f<<<dim3(96, 32), 256, 0, stream>>>(a, phi, s);
            lca_t_f<<<dim3(64, 4), 512, 0, stream>>>(s, phi, b, u, a, lamp);
        }
    }
}

// Round 4
// 2038.561 us; speedup vs baseline: 1.9339x; 1.9339x over previous
//
#include <hip/hip_runtime.h>
#include <hip/hip_cooperative_groups.h>

namespace cg = cooperative_groups;

#define BATCH 32
#define PIX   3072
#define NEU   4096
#define STEPS 99           // reference runs NUM_STEPS-1 = 99 update iterations
#define ETA   (0.001f / 0.03f)
#define NBLK  256

typedef __bf16 bf16x8 __attribute__((ext_vector_type(8)));
typedef float  f32x4  __attribute__((ext_vector_type(4)));

__device__ __forceinline__ float softt(float u, float lam) {
    return u > lam ? u - lam : (u < -lam ? u + lam : 0.0f);
}

// fp32 -> bf16 round-to-nearest-even
__device__ __forceinline__ unsigned short f2b(float f) {
    unsigned int u = __builtin_bit_cast(unsigned int, f);
    u = (u + 0x7FFFu + ((u >> 16) & 1u)) >> 16;
    return (unsigned short)u;
}

__device__ __forceinline__ bf16x8 ldfrag_g(const unsigned short* p) {
    uint4 v = *(const uint4*)p;
    return __builtin_bit_cast(bf16x8, v);
}

// ---------------------------------------------------------------------------
// φ (fp32 [PIX][NEU]) -> φT (bf16 [NEU][PIX]).  64x64 tiles via LDS.
// grid (NEU/64, PIX/64), block 256
__global__ void transp(const float* __restrict__ phi, unsigned short* __restrict__ phiT) {
    __shared__ float t[64][65];
    const int n0 = blockIdx.x * 64, p0 = blockIdx.y * 64;
    const int tid = threadIdx.x;
    #pragma unroll
    for (int pass = 0; pass < 4; ++pass) {
        const int r  = pass * 16 + (tid >> 4);
        const int c4 = (tid & 15) * 4;
        float4 v = *(const float4*)(phi + (size_t)(p0 + r) * NEU + n0 + c4);
        t[r][c4 + 0] = v.x; t[r][c4 + 1] = v.y; t[r][c4 + 2] = v.z; t[r][c4 + 3] = v.w;
    }
    __syncthreads();
    #pragma unroll
    for (int pass = 0; pass < 2; ++pass) {
        const int cp = pass * 32 + (tid >> 3);   // n-column -> φT row
        const int p8 = (tid & 7) * 8;            // 8 consecutive p
        unsigned int w0 = (unsigned int)f2b(t[p8 + 0][cp]) | ((unsigned int)f2b(t[p8 + 1][cp]) << 16);
        unsigned int w1 = (unsigned int)f2b(t[p8 + 2][cp]) | ((unsigned int)f2b(t[p8 + 3][cp]) << 16);
        unsigned int w2 = (unsigned int)f2b(t[p8 + 4][cp]) | ((unsigned int)f2b(t[p8 + 5][cp]) << 16);
        unsigned int w3 = (unsigned int)f2b(t[p8 + 6][cp]) | ((unsigned int)f2b(t[p8 + 7][cp]) << 16);
        uint4 o = make_uint4(w0, w1, w2, w3);
        *(uint4*)(phiT + (size_t)(n0 + cp) * PIX + p0 + p8) = o;
    }
}

// ---------------------------------------------------------------------------
// G = φᵀφ (symmetric, bf16). Upper-triangle blocks only; mirror-store.
__global__ void gemm_G(const unsigned short* __restrict__ phiT, unsigned short* __restrict__ G) {
    if (blockIdx.y > blockIdx.x) return;       // keep m0 <= n0
    __shared__ __align__(16) unsigned short lds[2][128 * 40];
    const int m0 = blockIdx.y * 128, n0 = blockIdx.x * 128;
    const int tid  = threadIdx.x;
    const int lane = tid & 63, w = tid >> 6;
    const int wm = (w & 1) * 64, wn = (w >> 1) * 64;
    const int q8 = (lane >> 4) * 8, l15 = lane & 15;
    f32x4 acc[4][4] = {};
    for (int k0 = 0; k0 < PIX; k0 += 32) {
        __syncthreads();
        #pragma unroll
        for (int it = 0; it < 2; ++it) {
            const int id = tid + 256 * it;       // 0..511
            const int row = id >> 2, q = id & 3;
            uint4 va = *(const uint4*)(phiT + (size_t)(m0 + row) * PIX + k0 + q * 8);
            *(uint4*)(&lds[0][row * 40 + q * 8]) = va;
            uint4 vb = *(const uint4*)(phiT + (size_t)(n0 + row) * PIX + k0 + q * 8);
            *(uint4*)(&lds[1][row * 40 + q * 8]) = vb;
        }
        __syncthreads();
        bf16x8 af[4], bfr[4];
        #pragma unroll
        for (int i = 0; i < 4; ++i) {
            af[i]  = *(const bf16x8*)(&lds[0][(wm + i * 16 + l15) * 40 + q8]);
            bfr[i] = *(const bf16x8*)(&lds[1][(wn + i * 16 + l15) * 40 + q8]);
        }
        #pragma unroll
        for (int i = 0; i < 4; ++i)
            #pragma unroll
            for (int j = 0; j < 4; ++j)
                acc[i][j] = __builtin_amdgcn_mfma_f32_16x16x32_bf16(af[i], bfr[j], acc[i][j], 0, 0, 0);
    }
    const int q = lane >> 4;
    const bool offdiag = (blockIdx.y != blockIdx.x);
    #pragma unroll
    for (int i = 0; i < 4; ++i)
        #pragma unroll
        for (int j = 0; j < 4; ++j) {
            unsigned short pk[4];
            #pragma unroll
            for (int r = 0; r < 4; ++r) {
                const int gm = m0 + wm + i * 16 + q * 4 + r;
                const int gn = n0 + wn + j * 16 + l15;
                const unsigned short v = f2b(acc[i][j][r]);
                G[(size_t)gm * NEU + gn] = v;   // coalesced across l15
                pk[r] = v;
            }
            if (offdiag) {
                const int gm0 = m0 + wm + i * 16 + q * 4;
                const int gn  = n0 + wn + j * 16 + l15;
                *(ushort4*)(G + (size_t)gn * NEU + gm0) = make_ushort4(pk[0], pk[1], pk[2], pk[3]);
            }
        }
}

// ---------------------------------------------------------------------------
// b = x @ phi; zero a-ping buffer; zero the grid-barrier counter.
__global__ void lca_binit(const float* __restrict__ x, const unsigned short* __restrict__ phiT,
                          float* __restrict__ b, unsigned short* __restrict__ ab0,
                          unsigned int* __restrict__ cnt) {
    __shared__ float red[8 * 512];
    const int tid = threadIdx.x;
    const int lane = tid & 63, w = tid >> 6;
    const int n0 = blockIdx.x * 16;
    const int kbase = w * (PIX / 8);             // 384
    const int q8 = (lane >> 4) * 8, l15 = lane & 15;
    if (blockIdx.x == 0 && tid == 0) *cnt = 0u;
    f32x4 acc[2] = {};
    const unsigned short* Brow = phiT + (size_t)(n0 + l15) * PIX + kbase + q8;
    const float* X0 = x + (size_t)l15 * PIX + kbase + q8;
    const float* X1 = x + (size_t)(16 + l15) * PIX + kbase + q8;
    #pragma unroll 4
    for (int kk = 0; kk < PIX / 8; kk += 32) {
        bf16x8 bg = ldfrag_g(Brow + kk);
        float4 xa0 = *(const float4*)(X0 + kk), xb0 = *(const float4*)(X0 + kk + 4);
        float4 xa1 = *(const float4*)(X1 + kk), xb1 = *(const float4*)(X1 + kk + 4);
        bf16x8 a0, a1;
        a0[0]=(__bf16)xa0.x; a0[1]=(__bf16)xa0.y; a0[2]=(__bf16)xa0.z; a0[3]=(__bf16)xa0.w;
        a0[4]=(__bf16)xb0.x; a0[5]=(__bf16)xb0.y; a0[6]=(__bf16)xb0.z; a0[7]=(__bf16)xb0.w;
        a1[0]=(__bf16)xa1.x; a1[1]=(__bf16)xa1.y; a1[2]=(__bf16)xa1.z; a1[3]=(__bf16)xa1.w;
        a1[4]=(__bf16)xb1.x; a1[5]=(__bf16)xb1.y; a1[6]=(__bf16)xb1.z; a1[7]=(__bf16)xb1.w;
        acc[0] = __builtin_amdgcn_mfma_f32_16x16x32_bf16(a0, bg, acc[0], 0, 0, 0);
        acc[1] = __builtin_amdgcn_mfma_f32_16x16x32_bf16(a1, bg, acc[1], 0, 0, 0);
    }
    const int q = lane >> 4;
    #pragma unroll
    for (int mt = 0; mt < 2; ++mt)
        #pragma unroll
        for (int r = 0; r < 4; ++r)
            red[w * 512 + (mt * 16 + q * 4 + r) * 16 + l15] = acc[mt][r];
    __syncthreads();
    float s = 0.f;
    #pragma unroll
    for (int w8 = 0; w8 < 8; ++w8) s += red[w8 * 512 + tid];
    const int m = tid >> 4, n = n0 + (tid & 15);
    const size_t idx = (size_t)m * NEU + n;
    b[idx] = s; ab0[idx] = 0;
}

// ---------------------------------------------------------------------------
// Persistent kernel, custom fast grid barrier, G pinned in VGPRs.
__global__ void __launch_bounds__(512, 2)
lca_persist(const unsigned short* __restrict__ G, const float* __restrict__ b,
            unsigned short* __restrict__ ab0, unsigned short* __restrict__ ab1,
            float* __restrict__ aout, const float* __restrict__ lamp,
            unsigned int* __restrict__ cnt) {
    __shared__ float red[8 * 512];
    const int tid = threadIdx.x;
    const int lane = tid & 63, w = tid >> 6;
    const int n0 = blockIdx.x * 16;
    const int kbase = w * (NEU / 8);             // 512
    const int q8 = (lane >> 4) * 8, l15 = lane & 15;
    const int q = lane >> 4;

    // G fragments for this wave's k-range: loaded once, PINNED in VGPRs.
    bf16x8 gf[16];
    {
        const unsigned short* Grow = G + (size_t)(n0 + l15) * NEU + kbase + q8;
        #pragma unroll
        for (int it = 0; it < 16; ++it)
            gf[it] = ldfrag_g(Grow + it * 32);
    }
    #pragma unroll
    for (int it = 0; it < 16; ++it) {
        f32x4* pin = (f32x4*)&gf[it];
        asm volatile("" : "+v"(*pin));    // opaque def: forbids re-load inside loop
    }

    const int m = tid >> 4;
    const size_t idx = (size_t)m * NEU + n0 + (tid & 15);
    float bv = b[idx];
    float uv = 0.f, av = 0.f;
    const float lam = lamp[0];

    for (int step = 0; step < STEPS; ++step) {
        const unsigned short* rd = (step & 1) ? ab1 : ab0;
        unsigned short*       wr = (step & 1) ? ab0 : ab1;
        const unsigned short* A0 = rd + (size_t)l15 * NEU + kbase + q8;
        const unsigned short* A1 = rd + (size_t)(16 + l15) * NEU + kbase + q8;
        f32x4 acc0 = {}, acc1 = {};
        #pragma unroll
        for (int it = 0; it < 16; ++it) {
            bf16x8 a0 = ldfrag_g(A0 + it * 32);
            bf16x8 a1 = ldfrag_g(A1 + it * 32);
            acc0 = __builtin_amdgcn_mfma_f32_16x16x32_bf16(a0, gf[it], acc0, 0, 0, 0);
            acc1 = __builtin_amdgcn_mfma_f32_16x16x32_bf16(a1, gf[it], acc1, 0, 0, 0);
        }
        #pragma unroll
        for (int r = 0; r < 4; ++r) {
            red[w * 512 + (q * 4 + r) * 16 + l15]      = acc0[r];
            red[w * 512 + (16 + q * 4 + r) * 16 + l15] = acc1[r];
        }
        __syncthreads();
        float s = 0.f;
        #pragma unroll
        for (int w8 = 0; w8 < 8; ++w8) s += red[w8 * 512 + tid];
        const float du = bv - s + av - uv;
        uv = fmaf(ETA, du, uv);
        av = softt(uv, lam);

        if (step == STEPS - 1) {
            aout[idx] = av;              // last step: no publish, no barrier
        } else {
            wr[idx] = f2b(av);
            // ---- custom grid barrier (agent scope) ----
            __syncthreads();             // drains block's stores (vmcnt 0 + s_barrier)
            if (tid == 0) {
                __hip_atomic_fetch_add(cnt, 1u, __ATOMIC_RELEASE, __HIP_MEMORY_SCOPE_AGENT);
                const unsigned int target = (unsigned int)NBLK * (unsigned int)(step + 1);
                while (__hip_atomic_load(cnt, __ATOMIC_RELAXED, __HIP_MEMORY_SCOPE_AGENT) < target)
                    __builtin_amdgcn_s_sleep(1);
                __builtin_amdgcn_fence(__ATOMIC_ACQUIRE, "agent");  // L1/L2 inv before release
            }
            __syncthreads();             // also gates red[] reuse
        }
    }
}

// ===========================================================================
// Fallback fp32 path (round-1, known correct) for small ws_size
// ===========================================================================
__global__ void lca_init_f(const float* __restrict__ x, const float* __restrict__ phi,
                           float* __restrict__ b, float* __restrict__ u,
                           float* __restrict__ a) {
    const int n  = blockIdx.x * 64 + (threadIdx.x & 63);
    const int bi = blockIdx.y * 4 + (threadIdx.x >> 6);
    const float* xr = x + bi * PIX;
    float acc = 0.f;
    #pragma unroll 4
    for (int p = 0; p < PIX; ++p) acc = fmaf(xr[p], phi[p * NEU + n], acc);
    const int idx = bi * NEU + n;
    b[idx] = acc; u[idx] = 0.f; a[idx] = 0.f;
}
__global__ void lca_s_f(const float* __restrict__ a, const float* __restrict__ phi,
                        float* __restrict__ s) {
    const int lane = threadIdx.x & 63, w = threadIdx.x >> 6;
    const int bi = blockIdx.y, p0 = (blockIdx.x * 4 + w) * 8;
    const float* ar = a + bi * NEU;
    float acc[8] = {};
    for (int i = 0; i < NEU / 64; ++i) {
        const int n = i * 64 + lane;
        const float av = ar[n];
        #pragma unroll
        for (int j = 0; j < 8; ++j) acc[j] = fmaf(av, phi[(p0 + j) * NEU + n], acc[j]);
    }
    float out = 0.f;
    #pragma unroll
    for (int j = 0; j < 8; ++j) {
        float v = acc[j];
        v += __shfl_xor(v, 1, 64); v += __shfl_xor(v, 2, 64); v += __shfl_xor(v, 4, 64);
        v += __shfl_xor(v, 8, 64); v += __shfl_xor(v, 16, 64); v += __shfl_xor(v, 32, 64);
        if (lane == j) out = v;
    }
    if (lane < 8) s[bi * PIX + p0 + lane] = out;
}
__global__ void lca_t_f(const float* __restrict__ s, const float* __restrict__ phi,
                        const float* __restrict__ b, float* __restrict__ u,
                        float* __restrict__ a, const float* __restrict__ lamp) {
    __shared__ float ls[8 * 256];
    const int n = blockIdx.x * 64 + (threadIdx.x & 63);
    const int slot = threadIdx.x >> 6;
    const int bb = blockIdx.y * 8 + slot;
    float acc = 0.f;
    for (int c = 0; c < PIX; c += 256) {
        __syncthreads();
        for (int e = threadIdx.x; e < 8 * 256; e += 512) {
            const int r = e >> 8, p = e & 255;
            ls[e] = s[(blockIdx.y * 8 + r) * PIX + c + p];
        }
        __syncthreads();
        const float* lrow = ls + slot * 256;
        #pragma unroll 8
        for (int p = 0; p < 256; ++p) acc = fmaf(lrow[p], phi[(c + p) * NEU + n], acc);
    }
    const float lam = lamp[0];
    const int idx = bb * NEU + n;
    const float uo = u[idx];
    const float du = b[idx] - acc + a[idx] - uo;
    const float un = fmaf(ETA, du, uo);
    u[idx] = un; a[idx] = softt(un, lam);
}

// ===========================================================================
extern "C" void kernel_launch(void* const* d_in, const int* in_sizes, int n_in,
                              void* d_out, int out_size, void* d_ws, size_t ws_size,
                              hipStream_t stream) {
    const float* x    = (const float*)d_in[0];
    const float* phi  = (const float*)d_in[1];
    const float* lamp = (const float*)d_in[2];
    float* a = (float*)d_out;
    char* ws = (char*)d_ws;

    const size_t PHIT_OFF = 0;
    const size_t G_OFF    = PHIT_OFF + (size_t)NEU * PIX * 2;       // 24 MB
    const size_t B_OFF    = G_OFF    + (size_t)NEU * NEU * 2;       // +32 MB
    const size_t AB0_OFF  = B_OFF    + (size_t)BATCH * NEU * 4;
    const size_t AB1_OFF  = AB0_OFF  + (size_t)BATCH * NEU * 2;
    const size_t CNT_OFF  = AB1_OFF  + (size_t)BATCH * NEU * 2;
    const size_t NEED     = CNT_OFF  + 256;                         // ~57.3 MB

    if (ws_size >= NEED) {
        unsigned short* phiT = (unsigned short*)(ws + PHIT_OFF);
        unsigned short* G    = (unsigned short*)(ws + G_OFF);
        float*          b    = (float*)(ws + B_OFF);
        unsigned short* ab0  = (unsigned short*)(ws + AB0_OFF);
        unsigned short* ab1  = (unsigned short*)(ws + AB1_OFF);
        unsigned int*   cnt  = (unsigned int*)(ws + CNT_OFF);

        transp<<<dim3(NEU / 64, PIX / 64), 256, 0, stream>>>(phi, phiT);
        gemm_G<<<dim3(32, 32), 256, 0, stream>>>(phiT, G);
        lca_binit<<<NBLK, 512, 0, stream>>>(x, phiT, b, ab0, cnt);

        void* args[7];
        const unsigned short* Gc = G;
        const float* bc = b;
        const float* lc = lamp;
        args[0] = (void*)&Gc;
        args[1] = (void*)&bc;
        args[2] = (void*)&ab0;
        args[3] = (void*)&ab1;
        args[4] = (void*)&a;
        args[5] = (void*)&lc;
        args[6] = (void*)&cnt;
        hipLaunchCooperativeKernel((const void*)lca_persist, dim3(NBLK), dim3(512),
                                   args, 0, stream);
    } else {
        float* fws = (float*)d_ws;
        float* b = fws;
        float* u = fws + BATCH * NEU;
        float* s = fws + 2 * BATCH * NEU;
        lca_init_f<<<dim3(64, 8), 256, 0, stream>>>(x, phi, b, u, a);
        for (int it = 0; it < STEPS; ++it) {
            lca_s_f<<<dim3(96, 32), 256, 0, stream>>>(a, phi, s);
            lca_t_f<<<dim3(64, 4), 512, 0, stream>>>(s, phi, b, u, a, lamp);
        }
    }
}

// Round 5
// 1899.324 us; speedup vs baseline: 2.0757x; 1.0733x over previous
//
#include <hip/hip_runtime.h>

#define BATCH 32
#define PIX   3072
#define NEU   4096
#define STEPS 99           // reference runs NUM_STEPS-1 = 99 update iterations
#define ETA   (0.001f / 0.03f)
#define NBLK  128
#define TPB   512

typedef __bf16 bf16x8 __attribute__((ext_vector_type(8)));
typedef float  f32x4  __attribute__((ext_vector_type(4)));

__device__ __forceinline__ float softt(float u, float lam) {
    return u > lam ? u - lam : (u < -lam ? u + lam : 0.0f);
}

// fp32 -> bf16 round-to-nearest-even
__device__ __forceinline__ unsigned short f2b(float f) {
    unsigned int u = __builtin_bit_cast(unsigned int, f);
    u = (u + 0x7FFFu + ((u >> 16) & 1u)) >> 16;
    return (unsigned short)u;
}

__device__ __forceinline__ bf16x8 ldfrag_g(const unsigned short* p) {
    uint4 v = *(const uint4*)p;
    return __builtin_bit_cast(bf16x8, v);
}

// 16-B fragment via two 8-B agent-scope relaxed atomic loads.
// Atomic => never rematerialized/duplicated by the compiler; sc0/sc1 => bypasses
// the non-coherent per-XCD L2 (reads the L3 coherence point). No fences needed.
__device__ __forceinline__ bf16x8 ld_a16(const unsigned long long* p) {
    unsigned long long lo = __hip_atomic_load(p,     __ATOMIC_RELAXED, __HIP_MEMORY_SCOPE_AGENT);
    unsigned long long hi = __hip_atomic_load(p + 1, __ATOMIC_RELAXED, __HIP_MEMORY_SCOPE_AGENT);
    ulonglong2 v; v.x = lo; v.y = hi;
    return __builtin_bit_cast(bf16x8, v);
}

// ---------------------------------------------------------------------------
// φ (fp32 [PIX][NEU]) -> φT (bf16 [NEU][PIX]).  64x64 tiles via LDS.
__global__ void transp(const float* __restrict__ phi, unsigned short* __restrict__ phiT) {
    __shared__ float t[64][65];
    const int n0 = blockIdx.x * 64, p0 = blockIdx.y * 64;
    const int tid = threadIdx.x;
    #pragma unroll
    for (int pass = 0; pass < 4; ++pass) {
        const int r  = pass * 16 + (tid >> 4);
        const int c4 = (tid & 15) * 4;
        float4 v = *(const float4*)(phi + (size_t)(p0 + r) * NEU + n0 + c4);
        t[r][c4 + 0] = v.x; t[r][c4 + 1] = v.y; t[r][c4 + 2] = v.z; t[r][c4 + 3] = v.w;
    }
    __syncthreads();
    #pragma unroll
    for (int pass = 0; pass < 2; ++pass) {
        const int cp = pass * 32 + (tid >> 3);
        const int p8 = (tid & 7) * 8;
        unsigned int w0 = (unsigned int)f2b(t[p8 + 0][cp]) | ((unsigned int)f2b(t[p8 + 1][cp]) << 16);
        unsigned int w1 = (unsigned int)f2b(t[p8 + 2][cp]) | ((unsigned int)f2b(t[p8 + 3][cp]) << 16);
        unsigned int w2 = (unsigned int)f2b(t[p8 + 4][cp]) | ((unsigned int)f2b(t[p8 + 5][cp]) << 16);
        unsigned int w3 = (unsigned int)f2b(t[p8 + 6][cp]) | ((unsigned int)f2b(t[p8 + 7][cp]) << 16);
        uint4 o = make_uint4(w0, w1, w2, w3);
        *(uint4*)(phiT + (size_t)(n0 + cp) * PIX + p0 + p8) = o;
    }
}

// ---------------------------------------------------------------------------
// G = φᵀφ (symmetric, bf16). Upper-triangle blocks only; mirror-store.
__global__ void gemm_G(const unsigned short* __restrict__ phiT, unsigned short* __restrict__ G) {
    if (blockIdx.y > blockIdx.x) return;
    __shared__ __align__(16) unsigned short lds[2][128 * 40];
    const int m0 = blockIdx.y * 128, n0 = blockIdx.x * 128;
    const int tid  = threadIdx.x;
    const int lane = tid & 63, w = tid >> 6;
    const int wm = (w & 1) * 64, wn = (w >> 1) * 64;
    const int q8 = (lane >> 4) * 8, l15 = lane & 15;
    f32x4 acc[4][4] = {};
    for (int k0 = 0; k0 < PIX; k0 += 32) {
        __syncthreads();
        #pragma unroll
        for (int it = 0; it < 2; ++it) {
            const int id = tid + 256 * it;
            const int row = id >> 2, q = id & 3;
            uint4 va = *(const uint4*)(phiT + (size_t)(m0 + row) * PIX + k0 + q * 8);
            *(uint4*)(&lds[0][row * 40 + q * 8]) = va;
            uint4 vb = *(const uint4*)(phiT + (size_t)(n0 + row) * PIX + k0 + q * 8);
            *(uint4*)(&lds[1][row * 40 + q * 8]) = vb;
        }
        __syncthreads();
        bf16x8 af[4], bfr[4];
        #pragma unroll
        for (int i = 0; i < 4; ++i) {
            af[i]  = *(const bf16x8*)(&lds[0][(wm + i * 16 + l15) * 40 + q8]);
            bfr[i] = *(const bf16x8*)(&lds[1][(wn + i * 16 + l15) * 40 + q8]);
        }
        #pragma unroll
        for (int i = 0; i < 4; ++i)
            #pragma unroll
            for (int j = 0; j < 4; ++j)
                acc[i][j] = __builtin_amdgcn_mfma_f32_16x16x32_bf16(af[i], bfr[j], acc[i][j], 0, 0, 0);
    }
    const int q = lane >> 4;
    const bool offdiag = (blockIdx.y != blockIdx.x);
    #pragma unroll
    for (int i = 0; i < 4; ++i)
        #pragma unroll
        for (int j = 0; j < 4; ++j) {
            unsigned short pk[4];
            #pragma unroll
            for (int r = 0; r < 4; ++r) {
                const int gm = m0 + wm + i * 16 + q * 4 + r;
                const int gn = n0 + wn + j * 16 + l15;
                const unsigned short v = f2b(acc[i][j][r]);
                G[(size_t)gm * NEU + gn] = v;
                pk[r] = v;
            }
            if (offdiag) {
                const int gm0 = m0 + wm + i * 16 + q * 4;
                const int gn  = n0 + wn + j * 16 + l15;
                *(ushort4*)(G + (size_t)gn * NEU + gm0) = make_ushort4(pk[0], pk[1], pk[2], pk[3]);
            }
        }
}

// ---------------------------------------------------------------------------
// b = x @ phi; zero a-ping buffer; zero the grid-barrier counter.
// grid 256 (16-col strips), block 512
__global__ void lca_binit(const float* __restrict__ x, const unsigned short* __restrict__ phiT,
                          float* __restrict__ b, unsigned short* __restrict__ ab0,
                          unsigned int* __restrict__ cnt) {
    __shared__ float red[8 * 512];
    const int tid = threadIdx.x;
    const int lane = tid & 63, w = tid >> 6;
    const int n0 = blockIdx.x * 16;
    const int kbase = w * (PIX / 8);
    const int q8 = (lane >> 4) * 8, l15 = lane & 15;
    if (blockIdx.x == 0 && tid == 0) *cnt = 0u;
    f32x4 acc[2] = {};
    const unsigned short* Brow = phiT + (size_t)(n0 + l15) * PIX + kbase + q8;
    const float* X0 = x + (size_t)l15 * PIX + kbase + q8;
    const float* X1 = x + (size_t)(16 + l15) * PIX + kbase + q8;
    #pragma unroll 4
    for (int kk = 0; kk < PIX / 8; kk += 32) {
        bf16x8 bg = ldfrag_g(Brow + kk);
        float4 xa0 = *(const float4*)(X0 + kk), xb0 = *(const float4*)(X0 + kk + 4);
        float4 xa1 = *(const float4*)(X1 + kk), xb1 = *(const float4*)(X1 + kk + 4);
        bf16x8 a0, a1;
        a0[0]=(__bf16)xa0.x; a0[1]=(__bf16)xa0.y; a0[2]=(__bf16)xa0.z; a0[3]=(__bf16)xa0.w;
        a0[4]=(__bf16)xb0.x; a0[5]=(__bf16)xb0.y; a0[6]=(__bf16)xb0.z; a0[7]=(__bf16)xb0.w;
        a1[0]=(__bf16)xa1.x; a1[1]=(__bf16)xa1.y; a1[2]=(__bf16)xa1.z; a1[3]=(__bf16)xa1.w;
        a1[4]=(__bf16)xb1.x; a1[5]=(__bf16)xb1.y; a1[6]=(__bf16)xb1.z; a1[7]=(__bf16)xb1.w;
        acc[0] = __builtin_amdgcn_mfma_f32_16x16x32_bf16(a0, bg, acc[0], 0, 0, 0);
        acc[1] = __builtin_amdgcn_mfma_f32_16x16x32_bf16(a1, bg, acc[1], 0, 0, 0);
    }
    const int q = lane >> 4;
    #pragma unroll
    for (int mt = 0; mt < 2; ++mt)
        #pragma unroll
        for (int r = 0; r < 4; ++r)
            red[w * 512 + (mt * 16 + q * 4 + r) * 16 + l15] = acc[mt][r];
    __syncthreads();
    float s = 0.f;
    #pragma unroll
    for (int w8 = 0; w8 < 8; ++w8) s += red[w8 * 512 + tid];
    const int m = tid >> 4, n = n0 + (tid & 15);
    const size_t idx = (size_t)m * NEU + n;
    b[idx] = s; ab0[idx] = 0;
}

// ---------------------------------------------------------------------------
// Persistent kernel. 128 blocks x 512 thr; block owns 32 columns.
// G fragments held in VGPRs via atomic loads (non-rematerializable).
// a ping-pong exchanged via agent-scope atomics (L2-bypassing) => no fences.
// NOTE: G/ab pointers deliberately NOT __restrict__ (blocks remat of G loads).
__global__ void __launch_bounds__(TPB, 2)
lca_persist(const unsigned short* G, const float* b,
            unsigned int* ab0, unsigned int* ab1,
            float* aout, const float* lamp, unsigned int* cnt) {
    __shared__ float red[8 * 1024];
    const int tid  = threadIdx.x;
    const int lane = tid & 63, w = tid >> 6;        // 8 waves
    const int l15  = lane & 15, q = lane >> 4;
    const int q8   = q * 8;
    const int n0   = blockIdx.x * 32;               // 32 columns per block
    const int kbase = w * (NEU / 8);                // 512 k per wave

    // --- G fragments: 2 n-tiles x 16 k-frags, pinned in registers ---
    bf16x8 gf[2][16];
    {
        const unsigned long long* G64 = (const unsigned long long*)G;
        #pragma unroll
        for (int j = 0; j < 2; ++j)
            #pragma unroll
            for (int f = 0; f < 16; ++f) {
                const size_t e = (size_t)(n0 + j * 16 + l15) * NEU + kbase + f * 32 + q8;
                gf[j][f] = ld_a16(G64 + (e >> 2));
            }
    }

    // --- per-thread state: outputs o0 = tid, o1 = tid + 512 (o = m*32 + nn) ---
    const int m0i = tid >> 5,        nn0 = tid & 31;
    const int m1i = (tid + 512) >> 5, nn1 = nn0;
    const size_t idx0 = (size_t)m0i * NEU + n0 + nn0;
    const size_t idx1 = (size_t)m1i * NEU + n0 + nn1;
    float bv0 = b[idx0], bv1 = b[idx1];
    float uv0 = 0.f, uv1 = 0.f, av0 = 0.f, av1 = 0.f;
    const float lam = lamp[0];

    const size_t aoff0 = ((size_t)l15 * NEU + kbase + q8) >> 2;        // in ULL units
    const size_t aoff1 = ((size_t)(16 + l15) * NEU + kbase + q8) >> 2;

    for (int step = 0; step < STEPS; ++step) {
        const unsigned long long* A64 = (const unsigned long long*)((step & 1) ? ab1 : ab0);
        unsigned int*             wrp = (step & 1) ? ab0 : ab1;

        f32x4 acc00 = {}, acc01 = {}, acc10 = {}, acc11 = {};
        #pragma unroll
        for (int f = 0; f < 16; ++f) {
            bf16x8 a0 = ld_a16(A64 + aoff0 + f * 8);
            bf16x8 a1 = ld_a16(A64 + aoff1 + f * 8);
            acc00 = __builtin_amdgcn_mfma_f32_16x16x32_bf16(a0, gf[0][f], acc00, 0, 0, 0);
            acc01 = __builtin_amdgcn_mfma_f32_16x16x32_bf16(a0, gf[1][f], acc01, 0, 0, 0);
            acc10 = __builtin_amdgcn_mfma_f32_16x16x32_bf16(a1, gf[0][f], acc10, 0, 0, 0);
            acc11 = __builtin_amdgcn_mfma_f32_16x16x32_bf16(a1, gf[1][f], acc11, 0, 0, 0);
        }
        // stage partials: red[w][ (m)*32 + nn ],  m = mt*16 + q*4 + r, nn = j*16 + l15
        #pragma unroll
        for (int r = 0; r < 4; ++r) {
            red[w * 1024 + (q * 4 + r) * 32 + l15]           = acc00[r];
            red[w * 1024 + (q * 4 + r) * 32 + 16 + l15]      = acc01[r];
            red[w * 1024 + (16 + q * 4 + r) * 32 + l15]      = acc10[r];
            red[w * 1024 + (16 + q * 4 + r) * 32 + 16 + l15] = acc11[r];
        }
        __syncthreads();
        float s0 = 0.f, s1 = 0.f;
        #pragma unroll
        for (int w8 = 0; w8 < 8; ++w8) {
            s0 += red[w8 * 1024 + tid];
            s1 += red[w8 * 1024 + 512 + tid];
        }
        uv0 = fmaf(ETA, bv0 - s0 + av0 - uv0, uv0);
        uv1 = fmaf(ETA, bv1 - s1 + av1 - uv1, uv1);
        av0 = softt(uv0, lam);
        av1 = softt(uv1, lam);

        if (step == STEPS - 1) {
            aout[idx0] = av0;
            aout[idx1] = av1;
        } else {
            // publish a: pack lane-pairs (nn even|odd) into one 4-B agent store
            unsigned int p0 = f2b(av0), p1 = f2b(av1);
            unsigned int t0 = (unsigned int)__shfl_xor((int)p0, 1, 64);
            unsigned int t1 = (unsigned int)__shfl_xor((int)p1, 1, 64);
            if ((tid & 1) == 0) {
                __hip_atomic_store(wrp + (idx0 >> 1), p0 | (t0 << 16),
                                   __ATOMIC_RELAXED, __HIP_MEMORY_SCOPE_AGENT);
                __hip_atomic_store(wrp + (idx1 >> 1), p1 | (t1 << 16),
                                   __ATOMIC_RELAXED, __HIP_MEMORY_SCOPE_AGENT);
            }
            // ---- fenceless grid barrier (stores are L2-bypassing) ----
            __syncthreads();     // per-wave vmcnt(0): all block stores at L3
            if (tid == 0) {
                __hip_atomic_fetch_add(cnt, 1u, __ATOMIC_RELAXED, __HIP_MEMORY_SCOPE_AGENT);
                const unsigned int target = (unsigned int)NBLK * (unsigned int)(step + 1);
                while (__hip_atomic_load(cnt, __ATOMIC_RELAXED, __HIP_MEMORY_SCOPE_AGENT) < target)
                    __builtin_amdgcn_s_sleep(1);
            }
            __syncthreads();     // release block; also gates red[] reuse
        }
    }
}

// ===========================================================================
// Fallback fp32 path (round-1, known correct) for small ws_size
// ===========================================================================
__global__ void lca_init_f(const float* __restrict__ x, const float* __restrict__ phi,
                           float* __restrict__ b, float* __restrict__ u,
                           float* __restrict__ a) {
    const int n  = blockIdx.x * 64 + (threadIdx.x & 63);
    const int bi = blockIdx.y * 4 + (threadIdx.x >> 6);
    const float* xr = x + bi * PIX;
    float acc = 0.f;
    #pragma unroll 4
    for (int p = 0; p < PIX; ++p) acc = fmaf(xr[p], phi[p * NEU + n], acc);
    const int idx = bi * NEU + n;
    b[idx] = acc; u[idx] = 0.f; a[idx] = 0.f;
}
__global__ void lca_s_f(const float* __restrict__ a, const float* __restrict__ phi,
                        float* __restrict__ s) {
    const int lane = threadIdx.x & 63, w = threadIdx.x >> 6;
    const int bi = blockIdx.y, p0 = (blockIdx.x * 4 + w) * 8;
    const float* ar = a + bi * NEU;
    float acc[8] = {};
    for (int i = 0; i < NEU / 64; ++i) {
        const int n = i * 64 + lane;
        const float av = ar[n];
        #pragma unroll
        for (int j = 0; j < 8; ++j) acc[j] = fmaf(av, phi[(p0 + j) * NEU + n], acc[j]);
    }
    float out = 0.f;
    #pragma unroll
    for (int j = 0; j < 8; ++j) {
        float v = acc[j];
        v += __shfl_xor(v, 1, 64); v += __shfl_xor(v, 2, 64); v += __shfl_xor(v, 4, 64);
        v += __shfl_xor(v, 8, 64); v += __shfl_xor(v, 16, 64); v += __shfl_xor(v, 32, 64);
        if (lane == j) out = v;
    }
    if (lane < 8) s[bi * PIX + p0 + lane] = out;
}
__global__ void lca_t_f(const float* __restrict__ s, const float* __restrict__ phi,
                        const float* __restrict__ b, float* __restrict__ u,
                        float* __restrict__ a, const float* __restrict__ lamp) {
    __shared__ float ls[8 * 256];
    const int n = blockIdx.x * 64 + (threadIdx.x & 63);
    const int slot = threadIdx.x >> 6;
    const int bb = blockIdx.y * 8 + slot;
    float acc = 0.f;
    for (int c = 0; c < PIX; c += 256) {
        __syncthreads();
        for (int e = threadIdx.x; e < 8 * 256; e += 512) {
            const int r = e >> 8, p = e & 255;
            ls[e] = s[(blockIdx.y * 8 + r) * PIX + c + p];
        }
        __syncthreads();
        const float* lrow = ls + slot * 256;
        #pragma unroll 8
        for (int p = 0; p < 256; ++p) acc = fmaf(lrow[p], phi[(c + p) * NEU + n], acc);
    }
    const float lam = lamp[0];
    const int idx = bb * NEU + n;
    const float uo = u[idx];
    const float du = b[idx] - acc + a[idx] - uo;
    const float un = fmaf(ETA, du, uo);
    u[idx] = un; a[idx] = softt(un, lam);
}

// ===========================================================================
extern "C" void kernel_launch(void* const* d_in, const int* in_sizes, int n_in,
                              void* d_out, int out_size, void* d_ws, size_t ws_size,
                              hipStream_t stream) {
    const float* x    = (const float*)d_in[0];
    const float* phi  = (const float*)d_in[1];
    const float* lamp = (const float*)d_in[2];
    float* a = (float*)d_out;
    char* ws = (char*)d_ws;

    const size_t PHIT_OFF = 0;
    const size_t G_OFF    = PHIT_OFF + (size_t)NEU * PIX * 2;       // 24 MB
    const size_t B_OFF    = G_OFF    + (size_t)NEU * NEU * 2;       // +32 MB
    const size_t AB0_OFF  = B_OFF    + (size_t)BATCH * NEU * 4;
    const size_t AB1_OFF  = AB0_OFF  + (size_t)BATCH * NEU * 2;
    const size_t CNT_OFF  = AB1_OFF  + (size_t)BATCH * NEU * 2;
    const size_t NEED     = CNT_OFF  + 256;                         // ~57.3 MB

    if (ws_size >= NEED) {
        unsigned short* phiT = (unsigned short*)(ws + PHIT_OFF);
        unsigned short* G    = (unsigned short*)(ws + G_OFF);
        float*          b    = (float*)(ws + B_OFF);
        unsigned int*   ab0  = (unsigned int*)(ws + AB0_OFF);
        unsigned int*   ab1  = (unsigned int*)(ws + AB1_OFF);
        unsigned int*   cnt  = (unsigned int*)(ws + CNT_OFF);

        transp<<<dim3(NEU / 64, PIX / 64), 256, 0, stream>>>(phi, phiT);
        gemm_G<<<dim3(32, 32), 256, 0, stream>>>(phiT, G);
        lca_binit<<<256, 512, 0, stream>>>(x, phiT, b, (unsigned short*)ab0, cnt);

        void* args[7];
        const unsigned short* Gc = G;
        const float* bc = b;
        const float* lc = lamp;
        args[0] = (void*)&Gc;
        args[1] = (void*)&bc;
        args[2] = (void*)&ab0;
        args[3] = (void*)&ab1;
        args[4] = (void*)&a;
        args[5] = (void*)&lc;
        args[6] = (void*)&cnt;
        hipLaunchCooperativeKernel((const void*)lca_persist, dim3(NBLK), dim3(TPB),
                                   args, 0, stream);
    } else {
        float* fws = (float*)d_ws;
        float* b = fws;
        float* u = fws + BATCH * NEU;
        float* s = fws + 2 * BATCH * NEU;
        lca_init_f<<<dim3(64, 8), 256, 0, stream>>>(x, phi, b, u, a);
        for (int it = 0; it < STEPS; ++it) {
            lca_s_f<<<dim3(96, 32), 256, 0, stream>>>(a, phi, s);
            lca_t_f<<<dim3(64, 4), 512, 0, stream>>>(s, phi, b, u, a, lamp);
        }
    }
}

// Round 6
// 1825.905 us; speedup vs baseline: 2.1592x; 1.0402x over previous
//
#include <hip/hip_runtime.h>

#define BATCH 32
#define PIX   3072
#define NEU   4096
#define STEPS 99           // reference runs NUM_STEPS-1 = 99 update iterations
#define ETA   (0.001f / 0.03f)
#define NBLK  128
#define TPB   512

typedef __bf16 bf16x8 __attribute__((ext_vector_type(8)));
typedef float  f32x4  __attribute__((ext_vector_type(4)));

__device__ __forceinline__ float softt(float u, float lam) {
    return u > lam ? u - lam : (u < -lam ? u + lam : 0.0f);
}

// fp32 -> bf16 round-to-nearest-even
__device__ __forceinline__ unsigned short f2b(float f) {
    unsigned int u = __builtin_bit_cast(unsigned int, f);
    u = (u + 0x7FFFu + ((u >> 16) & 1u)) >> 16;
    return (unsigned short)u;
}

__device__ __forceinline__ bf16x8 ldfrag_g(const unsigned short* p) {
    uint4 v = *(const uint4*)p;
    return __builtin_bit_cast(bf16x8, v);
}

// 16-B fragment via two 8-B agent-scope relaxed atomic loads (L2-bypassing,
// non-rematerializable).
__device__ __forceinline__ bf16x8 ld_a16(const unsigned long long* p) {
    unsigned long long lo = __hip_atomic_load(p,     __ATOMIC_RELAXED, __HIP_MEMORY_SCOPE_AGENT);
    unsigned long long hi = __hip_atomic_load(p + 1, __ATOMIC_RELAXED, __HIP_MEMORY_SCOPE_AGENT);
    ulonglong2 v; v.x = lo; v.y = hi;
    return __builtin_bit_cast(bf16x8, v);
}

// ---------------------------------------------------------------------------
// φ (fp32 [PIX][NEU]) -> φT (bf16 [NEU][PIX]).  64x64 tiles via LDS.
__global__ void transp(const float* __restrict__ phi, unsigned short* __restrict__ phiT) {
    __shared__ float t[64][65];
    const int n0 = blockIdx.x * 64, p0 = blockIdx.y * 64;
    const int tid = threadIdx.x;
    #pragma unroll
    for (int pass = 0; pass < 4; ++pass) {
        const int r  = pass * 16 + (tid >> 4);
        const int c4 = (tid & 15) * 4;
        float4 v = *(const float4*)(phi + (size_t)(p0 + r) * NEU + n0 + c4);
        t[r][c4 + 0] = v.x; t[r][c4 + 1] = v.y; t[r][c4 + 2] = v.z; t[r][c4 + 3] = v.w;
    }
    __syncthreads();
    #pragma unroll
    for (int pass = 0; pass < 2; ++pass) {
        const int cp = pass * 32 + (tid >> 3);
        const int p8 = (tid & 7) * 8;
        unsigned int w0 = (unsigned int)f2b(t[p8 + 0][cp]) | ((unsigned int)f2b(t[p8 + 1][cp]) << 16);
        unsigned int w1 = (unsigned int)f2b(t[p8 + 2][cp]) | ((unsigned int)f2b(t[p8 + 3][cp]) << 16);
        unsigned int w2 = (unsigned int)f2b(t[p8 + 4][cp]) | ((unsigned int)f2b(t[p8 + 5][cp]) << 16);
        unsigned int w3 = (unsigned int)f2b(t[p8 + 6][cp]) | ((unsigned int)f2b(t[p8 + 7][cp]) << 16);
        uint4 o = make_uint4(w0, w1, w2, w3);
        *(uint4*)(phiT + (size_t)(n0 + cp) * PIX + p0 + p8) = o;
    }
}

// ---------------------------------------------------------------------------
// G = φᵀφ (symmetric, bf16). Upper-triangle blocks only; mirror-store.
__global__ void gemm_G(const unsigned short* __restrict__ phiT, unsigned short* __restrict__ G) {
    if (blockIdx.y > blockIdx.x) return;
    __shared__ __align__(16) unsigned short lds[2][128 * 40];
    const int m0 = blockIdx.y * 128, n0 = blockIdx.x * 128;
    const int tid  = threadIdx.x;
    const int lane = tid & 63, w = tid >> 6;
    const int wm = (w & 1) * 64, wn = (w >> 1) * 64;
    const int q8 = (lane >> 4) * 8, l15 = lane & 15;
    f32x4 acc[4][4] = {};
    for (int k0 = 0; k0 < PIX; k0 += 32) {
        __syncthreads();
        #pragma unroll
        for (int it = 0; it < 2; ++it) {
            const int id = tid + 256 * it;
            const int row = id >> 2, q = id & 3;
            uint4 va = *(const uint4*)(phiT + (size_t)(m0 + row) * PIX + k0 + q * 8);
            *(uint4*)(&lds[0][row * 40 + q * 8]) = va;
            uint4 vb = *(const uint4*)(phiT + (size_t)(n0 + row) * PIX + k0 + q * 8);
            *(uint4*)(&lds[1][row * 40 + q * 8]) = vb;
        }
        __syncthreads();
        bf16x8 af[4], bfr[4];
        #pragma unroll
        for (int i = 0; i < 4; ++i) {
            af[i]  = *(const bf16x8*)(&lds[0][(wm + i * 16 + l15) * 40 + q8]);
            bfr[i] = *(const bf16x8*)(&lds[1][(wn + i * 16 + l15) * 40 + q8]);
        }
        #pragma unroll
        for (int i = 0; i < 4; ++i)
            #pragma unroll
            for (int j = 0; j < 4; ++j)
                acc[i][j] = __builtin_amdgcn_mfma_f32_16x16x32_bf16(af[i], bfr[j], acc[i][j], 0, 0, 0);
    }
    const int q = lane >> 4;
    const bool offdiag = (blockIdx.y != blockIdx.x);
    #pragma unroll
    for (int i = 0; i < 4; ++i)
        #pragma unroll
        for (int j = 0; j < 4; ++j) {
            unsigned short pk[4];
            #pragma unroll
            for (int r = 0; r < 4; ++r) {
                const int gm = m0 + wm + i * 16 + q * 4 + r;
                const int gn = n0 + wn + j * 16 + l15;
                const unsigned short v = f2b(acc[i][j][r]);
                G[(size_t)gm * NEU + gn] = v;
                pk[r] = v;
            }
            if (offdiag) {
                const int gm0 = m0 + wm + i * 16 + q * 4;
                const int gn  = n0 + wn + j * 16 + l15;
                *(ushort4*)(G + (size_t)gn * NEU + gm0) = make_ushort4(pk[0], pk[1], pk[2], pk[3]);
            }
        }
}

// ---------------------------------------------------------------------------
// b = x @ phi; zero a-ping buffer; zero the 128 barrier flags (64-B padded).
// grid 256 (16-col strips), block 512
__global__ void lca_binit(const float* __restrict__ x, const unsigned short* __restrict__ phiT,
                          float* __restrict__ b, unsigned short* __restrict__ ab0,
                          unsigned int* __restrict__ arr) {
    __shared__ float red[8 * 512];
    const int tid = threadIdx.x;
    const int lane = tid & 63, w = tid >> 6;
    const int n0 = blockIdx.x * 16;
    const int kbase = w * (PIX / 8);
    const int q8 = (lane >> 4) * 8, l15 = lane & 15;
    if (blockIdx.x < NBLK && tid < 16) arr[blockIdx.x * 16 + tid] = 0u;
    f32x4 acc[2] = {};
    const unsigned short* Brow = phiT + (size_t)(n0 + l15) * PIX + kbase + q8;
    const float* X0 = x + (size_t)l15 * PIX + kbase + q8;
    const float* X1 = x + (size_t)(16 + l15) * PIX + kbase + q8;
    #pragma unroll 4
    for (int kk = 0; kk < PIX / 8; kk += 32) {
        bf16x8 bg = ldfrag_g(Brow + kk);
        float4 xa0 = *(const float4*)(X0 + kk), xb0 = *(const float4*)(X0 + kk + 4);
        float4 xa1 = *(const float4*)(X1 + kk), xb1 = *(const float4*)(X1 + kk + 4);
        bf16x8 a0, a1;
        a0[0]=(__bf16)xa0.x; a0[1]=(__bf16)xa0.y; a0[2]=(__bf16)xa0.z; a0[3]=(__bf16)xa0.w;
        a0[4]=(__bf16)xb0.x; a0[5]=(__bf16)xb0.y; a0[6]=(__bf16)xb0.z; a0[7]=(__bf16)xb0.w;
        a1[0]=(__bf16)xa1.x; a1[1]=(__bf16)xa1.y; a1[2]=(__bf16)xa1.z; a1[3]=(__bf16)xa1.w;
        a1[4]=(__bf16)xb1.x; a1[5]=(__bf16)xb1.y; a1[6]=(__bf16)xb1.z; a1[7]=(__bf16)xb1.w;
        acc[0] = __builtin_amdgcn_mfma_f32_16x16x32_bf16(a0, bg, acc[0], 0, 0, 0);
        acc[1] = __builtin_amdgcn_mfma_f32_16x16x32_bf16(a1, bg, acc[1], 0, 0, 0);
    }
    const int q = lane >> 4;
    #pragma unroll
    for (int mt = 0; mt < 2; ++mt)
        #pragma unroll
        for (int r = 0; r < 4; ++r)
            red[w * 512 + (mt * 16 + q * 4 + r) * 16 + l15] = acc[mt][r];
    __syncthreads();
    float s = 0.f;
    #pragma unroll
    for (int w8 = 0; w8 < 8; ++w8) s += red[w8 * 512 + tid];
    const int m = tid >> 4, n = n0 + (tid & 15);
    const size_t idx = (size_t)m * NEU + n;
    b[idx] = s; ab0[idx] = 0;
}

// ---------------------------------------------------------------------------
// Persistent kernel. 128 blocks x 512 thr; block owns 32 columns.
// Barrier = arrival-flag stores + all-blocks poll: ZERO atomic RMWs per step.
// A-frags loaded in 2 batches of 8 (latency paid twice, not 16x).
__global__ void __launch_bounds__(TPB, 2)
lca_persist(const unsigned short* G, const float* b,
            unsigned int* ab0, unsigned int* ab1,
            float* aout, const float* lamp, unsigned int* arr) {
    __shared__ float red[8 * 1024];
    const int tid  = threadIdx.x;
    const int lane = tid & 63, w = tid >> 6;        // 8 waves
    const int l15  = lane & 15, q = lane >> 4;
    const int q8   = q * 8;
    const int n0   = blockIdx.x * 32;               // 32 columns per block
    const int kbase = w * (NEU / 8);                // 512 k per wave

    // --- G fragments: 2 n-tiles x 16 k-frags, loaded once (atomic => no remat)
    bf16x8 gf[2][16];
    {
        const unsigned long long* G64 = (const unsigned long long*)G;
        #pragma unroll
        for (int j = 0; j < 2; ++j)
            #pragma unroll
            for (int f = 0; f < 16; ++f) {
                const size_t e = (size_t)(n0 + j * 16 + l15) * NEU + kbase + f * 32 + q8;
                gf[j][f] = ld_a16(G64 + (e >> 2));
            }
    }

    // --- per-thread state: outputs o0 = tid, o1 = tid + 512 (o = m*32 + nn) ---
    const int m0i = tid >> 5,         nn0 = tid & 31;
    const int m1i = (tid + 512) >> 5;
    const size_t idx0 = (size_t)m0i * NEU + n0 + nn0;
    const size_t idx1 = (size_t)m1i * NEU + n0 + nn0;
    float bv0 = b[idx0], bv1 = b[idx1];
    float uv0 = 0.f, uv1 = 0.f, av0 = 0.f, av1 = 0.f;
    const float lam = lamp[0];

    const size_t aoff0 = ((size_t)l15 * NEU + kbase + q8) >> 2;        // in ULL units
    const size_t aoff1 = ((size_t)(16 + l15) * NEU + kbase + q8) >> 2;

    for (int step = 0; step < STEPS; ++step) {
        const unsigned long long* A64 = (const unsigned long long*)((step & 1) ? ab1 : ab0);
        unsigned int*             wrp = (step & 1) ? ab0 : ab1;

        f32x4 acc00 = {}, acc01 = {}, acc10 = {}, acc11 = {};
        #pragma unroll
        for (int h = 0; h < 2; ++h) {                 // 2 batches of 8 frags
            bf16x8 s0[8], s1[8];
            #pragma unroll
            for (int f = 0; f < 8; ++f) {
                s0[f] = ld_a16(A64 + aoff0 + (h * 8 + f) * 8);
                s1[f] = ld_a16(A64 + aoff1 + (h * 8 + f) * 8);
            }
            #pragma unroll
            for (int f = 0; f < 8; ++f) {
                const int g = h * 8 + f;
                acc00 = __builtin_amdgcn_mfma_f32_16x16x32_bf16(s0[f], gf[0][g], acc00, 0, 0, 0);
                acc01 = __builtin_amdgcn_mfma_f32_16x16x32_bf16(s0[f], gf[1][g], acc01, 0, 0, 0);
                acc10 = __builtin_amdgcn_mfma_f32_16x16x32_bf16(s1[f], gf[0][g], acc10, 0, 0, 0);
                acc11 = __builtin_amdgcn_mfma_f32_16x16x32_bf16(s1[f], gf[1][g], acc11, 0, 0, 0);
            }
        }
        // stage partials: red[w][ m*32 + nn ],  m = mt*16 + q*4 + r, nn = j*16 + l15
        #pragma unroll
        for (int r = 0; r < 4; ++r) {
            red[w * 1024 + (q * 4 + r) * 32 + l15]           = acc00[r];
            red[w * 1024 + (q * 4 + r) * 32 + 16 + l15]      = acc01[r];
            red[w * 1024 + (16 + q * 4 + r) * 32 + l15]      = acc10[r];
            red[w * 1024 + (16 + q * 4 + r) * 32 + 16 + l15] = acc11[r];
        }
        __syncthreads();
        float s0 = 0.f, s1 = 0.f;
        #pragma unroll
        for (int w8 = 0; w8 < 8; ++w8) {
            s0 += red[w8 * 1024 + tid];
            s1 += red[w8 * 1024 + 512 + tid];
        }
        uv0 = fmaf(ETA, bv0 - s0 + av0 - uv0, uv0);
        uv1 = fmaf(ETA, bv1 - s1 + av1 - uv1, uv1);
        av0 = softt(uv0, lam);
        av1 = softt(uv1, lam);

        if (step == STEPS - 1) {
            aout[idx0] = av0;
            aout[idx1] = av1;
        } else {
            // publish a: pack lane-pairs (nn even|odd) into one 4-B agent store
            unsigned int p0 = f2b(av0), p1 = f2b(av1);
            unsigned int t0 = (unsigned int)__shfl_xor((int)p0, 1, 64);
            unsigned int t1 = (unsigned int)__shfl_xor((int)p1, 1, 64);
            if ((tid & 1) == 0) {
                __hip_atomic_store(wrp + (idx0 >> 1), p0 | (t0 << 16),
                                   __ATOMIC_RELAXED, __HIP_MEMORY_SCOPE_AGENT);
                __hip_atomic_store(wrp + (idx1 >> 1), p1 | (t1 << 16),
                                   __ATOMIC_RELAXED, __HIP_MEMORY_SCOPE_AGENT);
            }
            // ---- RMW-free grid barrier: flag store + all-blocks poll ----
            __syncthreads();     // vmcnt(0): this block's a-stores are at L3
            const unsigned int e = (unsigned int)(step + 1);
            if (tid == 0)
                __hip_atomic_store(arr + blockIdx.x * 16, e,
                                   __ATOMIC_RELAXED, __HIP_MEMORY_SCOPE_AGENT);
            if (tid < 64) {
                for (;;) {
                    unsigned int v0 = __hip_atomic_load(arr + tid * 16,
                                        __ATOMIC_RELAXED, __HIP_MEMORY_SCOPE_AGENT);
                    unsigned int v1 = __hip_atomic_load(arr + (tid + 64) * 16,
                                        __ATOMIC_RELAXED, __HIP_MEMORY_SCOPE_AGENT);
                    if (__ballot((v0 < e) || (v1 < e)) == 0ULL) break;
                    __builtin_amdgcn_s_sleep(1);
                }
            }
            __syncthreads();     // release block; also gates red[] reuse
        }
    }
}

// ===========================================================================
// Fallback fp32 path (round-1, known correct) for small ws_size
// ===========================================================================
__global__ void lca_init_f(const float* __restrict__ x, const float* __restrict__ phi,
                           float* __restrict__ b, float* __restrict__ u,
                           float* __restrict__ a) {
    const int n  = blockIdx.x * 64 + (threadIdx.x & 63);
    const int bi = blockIdx.y * 4 + (threadIdx.x >> 6);
    const float* xr = x + bi * PIX;
    float acc = 0.f;
    #pragma unroll 4
    for (int p = 0; p < PIX; ++p) acc = fmaf(xr[p], phi[p * NEU + n], acc);
    const int idx = bi * NEU + n;
    b[idx] = acc; u[idx] = 0.f; a[idx] = 0.f;
}
__global__ void lca_s_f(const float* __restrict__ a, const float* __restrict__ phi,
                        float* __restrict__ s) {
    const int lane = threadIdx.x & 63, w = threadIdx.x >> 6;
    const int bi = blockIdx.y, p0 = (blockIdx.x * 4 + w) * 8;
    const float* ar = a + bi * NEU;
    float acc[8] = {};
    for (int i = 0; i < NEU / 64; ++i) {
        const int n = i * 64 + lane;
        const float av = ar[n];
        #pragma unroll
        for (int j = 0; j < 8; ++j) acc[j] = fmaf(av, phi[(p0 + j) * NEU + n], acc[j]);
    }
    float out = 0.f;
    #pragma unroll
    for (int j = 0; j < 8; ++j) {
        float v = acc[j];
        v += __shfl_xor(v, 1, 64); v += __shfl_xor(v, 2, 64); v += __shfl_xor(v, 4, 64);
        v += __shfl_xor(v, 8, 64); v += __shfl_xor(v, 16, 64); v += __shfl_xor(v, 32, 64);
        if (lane == j) out = v;
    }
    if (lane < 8) s[bi * PIX + p0 + lane] = out;
}
__global__ void lca_t_f(const float* __restrict__ s, const float* __restrict__ phi,
                        const float* __restrict__ b, float* __restrict__ u,
                        float* __restrict__ a, const float* __restrict__ lamp) {
    __shared__ float ls[8 * 256];
    const int n = blockIdx.x * 64 + (threadIdx.x & 63);
    const int slot = threadIdx.x >> 6;
    const int bb = blockIdx.y * 8 + slot;
    float acc = 0.f;
    for (int c = 0; c < PIX; c += 256) {
        __syncthreads();
        for (int e = threadIdx.x; e < 8 * 256; e += 512) {
            const int r = e >> 8, p = e & 255;
            ls[e] = s[(blockIdx.y * 8 + r) * PIX + c + p];
        }
        __syncthreads();
        const float* lrow = ls + slot * 256;
        #pragma unroll 8
        for (int p = 0; p < 256; ++p) acc = fmaf(lrow[p], phi[(c + p) * NEU + n], acc);
    }
    const float lam = lamp[0];
    const int idx = bb * NEU + n;
    const float uo = u[idx];
    const float du = b[idx] - acc + a[idx] - uo;
    const float un = fmaf(ETA, du, uo);
    u[idx] = un; a[idx] = softt(un, lam);
}

// ===========================================================================
extern "C" void kernel_launch(void* const* d_in, const int* in_sizes, int n_in,
                              void* d_out, int out_size, void* d_ws, size_t ws_size,
                              hipStream_t stream) {
    const float* x    = (const float*)d_in[0];
    const float* phi  = (const float*)d_in[1];
    const float* lamp = (const float*)d_in[2];
    float* a = (float*)d_out;
    char* ws = (char*)d_ws;

    const size_t PHIT_OFF = 0;
    const size_t G_OFF    = PHIT_OFF + (size_t)NEU * PIX * 2;       // 24 MB
    const size_t B_OFF    = G_OFF    + (size_t)NEU * NEU * 2;       // +32 MB
    const size_t AB0_OFF  = B_OFF    + (size_t)BATCH * NEU * 4;
    const size_t AB1_OFF  = AB0_OFF  + (size_t)BATCH * NEU * 2;
    const size_t ARR_OFF  = AB1_OFF  + (size_t)BATCH * NEU * 2;
    const size_t NEED     = ARR_OFF  + (size_t)NBLK * 64;           // ~57.3 MB

    if (ws_size >= NEED) {
        unsigned short* phiT = (unsigned short*)(ws + PHIT_OFF);
        unsigned short* G    = (unsigned short*)(ws + G_OFF);
        float*          b    = (float*)(ws + B_OFF);
        unsigned int*   ab0  = (unsigned int*)(ws + AB0_OFF);
        unsigned int*   ab1  = (unsigned int*)(ws + AB1_OFF);
        unsigned int*   arr  = (unsigned int*)(ws + ARR_OFF);

        transp<<<dim3(NEU / 64, PIX / 64), 256, 0, stream>>>(phi, phiT);
        gemm_G<<<dim3(32, 32), 256, 0, stream>>>(phiT, G);
        lca_binit<<<256, 512, 0, stream>>>(x, phiT, b, (unsigned short*)ab0, arr);

        void* args[7];
        const unsigned short* Gc = G;
        const float* bc = b;
        const float* lc = lamp;
        args[0] = (void*)&Gc;
        args[1] = (void*)&bc;
        args[2] = (void*)&ab0;
        args[3] = (void*)&ab1;
        args[4] = (void*)&a;
        args[5] = (void*)&lc;
        args[6] = (void*)&arr;
        hipLaunchCooperativeKernel((const void*)lca_persist, dim3(NBLK), dim3(TPB),
                                   args, 0, stream);
    } else {
        float* fws = (float*)d_ws;
        float* b = fws;
        float* u = fws + BATCH * NEU;
        float* s = fws + 2 * BATCH * NEU;
        lca_init_f<<<dim3(64, 8), 256, 0, stream>>>(x, phi, b, u, a);
        for (int it = 0; it < STEPS; ++it) {
            lca_s_f<<<dim3(96, 32), 256, 0, stream>>>(a, phi, s);
            lca_t_f<<<dim3(64, 4), 512, 0, stream>>>(s, phi, b, u, a, lamp);
        }
    }
}

// Round 7
// 1166.224 us; speedup vs baseline: 3.3805x; 1.5657x over previous
//
#include <hip/hip_runtime.h>

#define BATCH 32
#define PIX   3072
#define NEU   4096
#define STEPS 99           // reference runs NUM_STEPS-1 = 99 update iterations
#define ETA   (0.001f / 0.03f)
#define NBLK  128
#define TPB   512
#define SLOT  (BATCH * NEU)          // halves per rotating a-buffer (256 KB)

typedef __bf16 bf16x8 __attribute__((ext_vector_type(8)));
typedef float  f32x4  __attribute__((ext_vector_type(4)));

__device__ __forceinline__ float softt(float u, float lam) {
    return u > lam ? u - lam : (u < -lam ? u + lam : 0.0f);
}

// fp32 -> bf16 round-to-nearest-even
__device__ __forceinline__ unsigned short f2b(float f) {
    unsigned int u = __builtin_bit_cast(unsigned int, f);
    u = (u + 0x7FFFu + ((u >> 16) & 1u)) >> 16;
    return (unsigned short)u;
}

__device__ __forceinline__ bf16x8 ldfrag_g(const unsigned short* p) {
    uint4 v = *(const uint4*)p;
    return __builtin_bit_cast(bf16x8, v);
}

// ---------------------------------------------------------------------------
// φ (fp32 [PIX][NEU]) -> φT (bf16 [NEU][PIX]).  64x64 tiles via LDS.
__global__ void transp(const float* __restrict__ phi, unsigned short* __restrict__ phiT) {
    __shared__ float t[64][65];
    const int n0 = blockIdx.x * 64, p0 = blockIdx.y * 64;
    const int tid = threadIdx.x;
    #pragma unroll
    for (int pass = 0; pass < 4; ++pass) {
        const int r  = pass * 16 + (tid >> 4);
        const int c4 = (tid & 15) * 4;
        float4 v = *(const float4*)(phi + (size_t)(p0 + r) * NEU + n0 + c4);
        t[r][c4 + 0] = v.x; t[r][c4 + 1] = v.y; t[r][c4 + 2] = v.z; t[r][c4 + 3] = v.w;
    }
    __syncthreads();
    #pragma unroll
    for (int pass = 0; pass < 2; ++pass) {
        const int cp = pass * 32 + (tid >> 3);
        const int p8 = (tid & 7) * 8;
        unsigned int w0 = (unsigned int)f2b(t[p8 + 0][cp]) | ((unsigned int)f2b(t[p8 + 1][cp]) << 16);
        unsigned int w1 = (unsigned int)f2b(t[p8 + 2][cp]) | ((unsigned int)f2b(t[p8 + 3][cp]) << 16);
        unsigned int w2 = (unsigned int)f2b(t[p8 + 4][cp]) | ((unsigned int)f2b(t[p8 + 5][cp]) << 16);
        unsigned int w3 = (unsigned int)f2b(t[p8 + 6][cp]) | ((unsigned int)f2b(t[p8 + 7][cp]) << 16);
        uint4 o = make_uint4(w0, w1, w2, w3);
        *(uint4*)(phiT + (size_t)(n0 + cp) * PIX + p0 + p8) = o;
    }
}

// ---------------------------------------------------------------------------
// G = φᵀφ (symmetric, bf16). Upper-triangle blocks only; mirror-store.
__global__ void gemm_G(const unsigned short* __restrict__ phiT, unsigned short* __restrict__ G) {
    if (blockIdx.y > blockIdx.x) return;
    __shared__ __align__(16) unsigned short lds[2][128 * 40];
    const int m0 = blockIdx.y * 128, n0 = blockIdx.x * 128;
    const int tid  = threadIdx.x;
    const int lane = tid & 63, w = tid >> 6;
    const int wm = (w & 1) * 64, wn = (w >> 1) * 64;
    const int q8 = (lane >> 4) * 8, l15 = lane & 15;
    f32x4 acc[4][4] = {};
    for (int k0 = 0; k0 < PIX; k0 += 32) {
        __syncthreads();
        #pragma unroll
        for (int it = 0; it < 2; ++it) {
            const int id = tid + 256 * it;
            const int row = id >> 2, q = id & 3;
            uint4 va = *(const uint4*)(phiT + (size_t)(m0 + row) * PIX + k0 + q * 8);
            *(uint4*)(&lds[0][row * 40 + q * 8]) = va;
            uint4 vb = *(const uint4*)(phiT + (size_t)(n0 + row) * PIX + k0 + q * 8);
            *(uint4*)(&lds[1][row * 40 + q * 8]) = vb;
        }
        __syncthreads();
        bf16x8 af[4], bfr[4];
        #pragma unroll
        for (int i = 0; i < 4; ++i) {
            af[i]  = *(const bf16x8*)(&lds[0][(wm + i * 16 + l15) * 40 + q8]);
            bfr[i] = *(const bf16x8*)(&lds[1][(wn + i * 16 + l15) * 40 + q8]);
        }
        #pragma unroll
        for (int i = 0; i < 4; ++i)
            #pragma unroll
            for (int j = 0; j < 4; ++j)
                acc[i][j] = __builtin_amdgcn_mfma_f32_16x16x32_bf16(af[i], bfr[j], acc[i][j], 0, 0, 0);
    }
    const int q = lane >> 4;
    const bool offdiag = (blockIdx.y != blockIdx.x);
    #pragma unroll
    for (int i = 0; i < 4; ++i)
        #pragma unroll
        for (int j = 0; j < 4; ++j) {
            unsigned short pk[4];
            #pragma unroll
            for (int r = 0; r < 4; ++r) {
                const int gm = m0 + wm + i * 16 + q * 4 + r;
                const int gn = n0 + wn + j * 16 + l15;
                const unsigned short v = f2b(acc[i][j][r]);
                G[(size_t)gm * NEU + gn] = v;
                pk[r] = v;
            }
            if (offdiag) {
                const int gm0 = m0 + wm + i * 16 + q * 4;
                const int gn  = n0 + wn + j * 16 + l15;
                *(ushort4*)(G + (size_t)gn * NEU + gm0) = make_ushort4(pk[0], pk[1], pk[2], pk[3]);
            }
        }
}

// ---------------------------------------------------------------------------
// b = x @ phi; zero the 128 barrier flags (64-B padded).
// grid 256 (16-col strips), block 512
__global__ void lca_binit(const float* __restrict__ x, const unsigned short* __restrict__ phiT,
                          float* __restrict__ b, unsigned int* __restrict__ arr) {
    __shared__ float red[8 * 512];
    const int tid = threadIdx.x;
    const int lane = tid & 63, w = tid >> 6;
    const int n0 = blockIdx.x * 16;
    const int kbase = w * (PIX / 8);
    const int q8 = (lane >> 4) * 8, l15 = lane & 15;
    if (blockIdx.x < NBLK && tid < 16) arr[blockIdx.x * 16 + tid] = 0u;
    f32x4 acc[2] = {};
    const unsigned short* Brow = phiT + (size_t)(n0 + l15) * PIX + kbase + q8;
    const float* X0 = x + (size_t)l15 * PIX + kbase + q8;
    const float* X1 = x + (size_t)(16 + l15) * PIX + kbase + q8;
    #pragma unroll 4
    for (int kk = 0; kk < PIX / 8; kk += 32) {
        bf16x8 bg = ldfrag_g(Brow + kk);
        float4 xa0 = *(const float4*)(X0 + kk), xb0 = *(const float4*)(X0 + kk + 4);
        float4 xa1 = *(const float4*)(X1 + kk), xb1 = *(const float4*)(X1 + kk + 4);
        bf16x8 a0, a1;
        a0[0]=(__bf16)xa0.x; a0[1]=(__bf16)xa0.y; a0[2]=(__bf16)xa0.z; a0[3]=(__bf16)xa0.w;
        a0[4]=(__bf16)xb0.x; a0[5]=(__bf16)xb0.y; a0[6]=(__bf16)xb0.z; a0[7]=(__bf16)xb0.w;
        a1[0]=(__bf16)xa1.x; a1[1]=(__bf16)xa1.y; a1[2]=(__bf16)xa1.z; a1[3]=(__bf16)xa1.w;
        a1[4]=(__bf16)xb1.x; a1[5]=(__bf16)xb1.y; a1[6]=(__bf16)xb1.z; a1[7]=(__bf16)xb1.w;
        acc[0] = __builtin_amdgcn_mfma_f32_16x16x32_bf16(a0, bg, acc[0], 0, 0, 0);
        acc[1] = __builtin_amdgcn_mfma_f32_16x16x32_bf16(a1, bg, acc[1], 0, 0, 0);
    }
    const int q = lane >> 4;
    #pragma unroll
    for (int mt = 0; mt < 2; ++mt)
        #pragma unroll
        for (int r = 0; r < 4; ++r)
            red[w * 512 + (mt * 16 + q * 4 + r) * 16 + l15] = acc[mt][r];
    __syncthreads();
    float s = 0.f;
    #pragma unroll
    for (int w8 = 0; w8 < 8; ++w8) s += red[w8 * 512 + tid];
    const int m = tid >> 4, n = n0 + (tid & 15);
    b[(size_t)m * NEU + n] = s;
}

// ---------------------------------------------------------------------------
// RMW-free grid barrier: flag store + all-blocks poll.  Stores were already
// drained (write-through, ack'd at L3) by the preceding __syncthreads.
__device__ __forceinline__ void gridbar(unsigned int* arr, unsigned int e,
                                        int tid, int bx) {
    __syncthreads();     // vmcnt(0): this block's publish stores are at L3
    if (tid == 0)
        __hip_atomic_store(arr + bx * 16, e, __ATOMIC_RELAXED, __HIP_MEMORY_SCOPE_AGENT);
    if (tid < 64) {
        for (;;) {
            unsigned int v0 = __hip_atomic_load(arr + tid * 16,
                                __ATOMIC_RELAXED, __HIP_MEMORY_SCOPE_AGENT);
            unsigned int v1 = __hip_atomic_load(arr + (tid + 64) * 16,
                                __ATOMIC_RELAXED, __HIP_MEMORY_SCOPE_AGENT);
            if (__ballot((v0 < e) || (v1 < e)) == 0ULL) break;
            __builtin_amdgcn_s_sleep(1);
        }
    }
    __syncthreads();
    asm volatile("" ::: "memory");   // no load hoisting above the barrier
}

// publish this thread's two a-values into rotating buffer (write-through 4-B
// agent stores; lane-pair packing => one store per pair)
__device__ __forceinline__ void publish(unsigned int* dst, size_t idx0, size_t idx1,
                                        float av0, float av1, int tid) {
    unsigned int p0 = f2b(av0), p1 = f2b(av1);
    unsigned int t0 = (unsigned int)__shfl_xor((int)p0, 1, 64);
    unsigned int t1 = (unsigned int)__shfl_xor((int)p1, 1, 64);
    if ((tid & 1) == 0) {
        __hip_atomic_store(dst + (idx0 >> 1), p0 | (t0 << 16),
                           __ATOMIC_RELAXED, __HIP_MEMORY_SCOPE_AGENT);
        __hip_atomic_store(dst + (idx1 >> 1), p1 | (t1 << 16),
                           __ATOMIC_RELAXED, __HIP_MEMORY_SCOPE_AGENT);
    }
}

// ---------------------------------------------------------------------------
// Persistent kernel. 128 blocks x 512 thr; block owns 32 columns.
// a exchanged via 98 ROTATING buffers: every line written once (write-through)
// and read once (normal pipelined loads) => no stale-L2 risk, no fences,
// no serialized atomic loads on the critical path.
__global__ void __launch_bounds__(TPB, 2)
lca_persist(const unsigned short* G, const float* b,
            unsigned short* rot, float* aout, const float* lamp,
            unsigned int* arr) {
    __shared__ float red[8 * 1024];
    const int tid  = threadIdx.x;
    const int lane = tid & 63, w = tid >> 6;        // 8 waves
    const int l15  = lane & 15, q = lane >> 4;
    const int q8   = q * 8;
    const int n0   = blockIdx.x * 32;               // 32 columns per block
    const int kbase = w * (NEU / 8);                // 512 k per wave

    // --- G fragments: 2 n-tiles x 16 k-frags.  Normal pipelined loads; no
    // __restrict__ anywhere => publish stores may alias => remat illegal.
    bf16x8 gf[2][16];
    #pragma unroll
    for (int j = 0; j < 2; ++j)
        #pragma unroll
        for (int f = 0; f < 16; ++f)
            gf[j][f] = ldfrag_g(G + (size_t)(n0 + j * 16 + l15) * NEU + kbase + f * 32 + q8);

    // --- per-thread state: outputs o0 = tid, o1 = tid + 512 (o = m*32 + nn) ---
    const int m0i = tid >> 5,         nn0 = tid & 31;
    const int m1i = (tid + 512) >> 5;
    const size_t idx0 = (size_t)m0i * NEU + n0 + nn0;
    const size_t idx1 = (size_t)m1i * NEU + n0 + nn0;
    const float bv0 = b[idx0], bv1 = b[idx1];
    const float lam = lamp[0];

    // --- step 0 entirely in-register: u1 = ETA*b, a1 = soft(u1) ---
    float uv0 = ETA * bv0, uv1 = ETA * bv1;
    float av0 = softt(uv0, lam), av1 = softt(uv1, lam);

    const size_t aoff0 = (size_t)l15 * NEU + kbase + q8;         // halves
    const size_t aoff1 = (size_t)(16 + l15) * NEU + kbase + q8;

    publish((unsigned int*)rot, idx0, idx1, av0, av1, tid);      // rot[0]
    gridbar(arr, 1u, tid, blockIdx.x);

    for (int step = 1; step < STEPS; ++step) {       // steps 1..98
        const unsigned short* A = rot + (size_t)(step - 1) * SLOT;

        f32x4 acc00 = {}, acc01 = {}, acc10 = {}, acc11 = {};
        #pragma unroll
        for (int h = 0; h < 2; ++h) {                // 2 batches of 8 frags
            bf16x8 s0[8], s1[8];
            #pragma unroll
            for (int f = 0; f < 8; ++f) {
                s0[f] = ldfrag_g(A + aoff0 + (h * 8 + f) * 32);
                s1[f] = ldfrag_g(A + aoff1 + (h * 8 + f) * 32);
            }
            #pragma unroll
            for (int f = 0; f < 8; ++f) {
                const int g = h * 8 + f;
                acc00 = __builtin_amdgcn_mfma_f32_16x16x32_bf16(s0[f], gf[0][g], acc00, 0, 0, 0);
                acc01 = __builtin_amdgcn_mfma_f32_16x16x32_bf16(s0[f], gf[1][g], acc01, 0, 0, 0);
                acc10 = __builtin_amdgcn_mfma_f32_16x16x32_bf16(s1[f], gf[0][g], acc10, 0, 0, 0);
                acc11 = __builtin_amdgcn_mfma_f32_16x16x32_bf16(s1[f], gf[1][g], acc11, 0, 0, 0);
            }
        }
        // stage partials: red[w][ m*32 + nn ],  m = mt*16 + q*4 + r, nn = j*16 + l15
        #pragma unroll
        for (int r = 0; r < 4; ++r) {
            red[w * 1024 + (q * 4 + r) * 32 + l15]           = acc00[r];
            red[w * 1024 + (q * 4 + r) * 32 + 16 + l15]      = acc01[r];
            red[w * 1024 + (16 + q * 4 + r) * 32 + l15]      = acc10[r];
            red[w * 1024 + (16 + q * 4 + r) * 32 + 16 + l15] = acc11[r];
        }
        __syncthreads();
        float s0 = 0.f, s1 = 0.f;
        #pragma unroll
        for (int w8 = 0; w8 < 8; ++w8) {
            s0 += red[w8 * 1024 + tid];
            s1 += red[w8 * 1024 + 512 + tid];
        }
        uv0 = fmaf(ETA, bv0 - s0 + av0 - uv0, uv0);
        uv1 = fmaf(ETA, bv1 - s1 + av1 - uv1, uv1);
        av0 = softt(uv0, lam);
        av1 = softt(uv1, lam);

        if (step == STEPS - 1) {
            aout[idx0] = av0;
            aout[idx1] = av1;
        } else {
            publish((unsigned int*)(rot + (size_t)step * SLOT), idx0, idx1, av0, av1, tid);
            gridbar(arr, (unsigned int)(step + 1), tid, blockIdx.x);
        }
    }
}

// ===========================================================================
// Fallback fp32 path (round-1, known correct) for small ws_size
// ===========================================================================
__global__ void lca_init_f(const float* __restrict__ x, const float* __restrict__ phi,
                           float* __restrict__ b, float* __restrict__ u,
                           float* __restrict__ a) {
    const int n  = blockIdx.x * 64 + (threadIdx.x & 63);
    const int bi = blockIdx.y * 4 + (threadIdx.x >> 6);
    const float* xr = x + bi * PIX;
    float acc = 0.f;
    #pragma unroll 4
    for (int p = 0; p < PIX; ++p) acc = fmaf(xr[p], phi[p * NEU + n], acc);
    const int idx = bi * NEU + n;
    b[idx] = acc; u[idx] = 0.f; a[idx] = 0.f;
}
__global__ void lca_s_f(const float* __restrict__ a, const float* __restrict__ phi,
                        float* __restrict__ s) {
    const int lane = threadIdx.x & 63, w = threadIdx.x >> 6;
    const int bi = blockIdx.y, p0 = (blockIdx.x * 4 + w) * 8;
    const float* ar = a + bi * NEU;
    float acc[8] = {};
    for (int i = 0; i < NEU / 64; ++i) {
        const int n = i * 64 + lane;
        const float av = ar[n];
        #pragma unroll
        for (int j = 0; j < 8; ++j) acc[j] = fmaf(av, phi[(p0 + j) * NEU + n], acc[j]);
    }
    float out = 0.f;
    #pragma unroll
    for (int j = 0; j < 8; ++j) {
        float v = acc[j];
        v += __shfl_xor(v, 1, 64); v += __shfl_xor(v, 2, 64); v += __shfl_xor(v, 4, 64);
        v += __shfl_xor(v, 8, 64); v += __shfl_xor(v, 16, 64); v += __shfl_xor(v, 32, 64);
        if (lane == j) out = v;
    }
    if (lane < 8) s[bi * PIX + p0 + lane] = out;
}
__global__ void lca_t_f(const float* __restrict__ s, const float* __restrict__ phi,
                        const float* __restrict__ b, float* __restrict__ u,
                        float* __restrict__ a, const float* __restrict__ lamp) {
    __shared__ float ls[8 * 256];
    const int n = blockIdx.x * 64 + (threadIdx.x & 63);
    const int slot = threadIdx.x >> 6;
    const int bb = blockIdx.y * 8 + slot;
    float acc = 0.f;
    for (int c = 0; c < PIX; c += 256) {
        __syncthreads();
        for (int e = threadIdx.x; e < 8 * 256; e += 512) {
            const int r = e >> 8, p = e & 255;
            ls[e] = s[(blockIdx.y * 8 + r) * PIX + c + p];
        }
        __syncthreads();
        const float* lrow = ls + slot * 256;
        #pragma unroll 8
        for (int p = 0; p < 256; ++p) acc = fmaf(lrow[p], phi[(c + p) * NEU + n], acc);
    }
    const float lam = lamp[0];
    const int idx = bb * NEU + n;
    const float uo = u[idx];
    const float du = b[idx] - acc + a[idx] - uo;
    const float un = fmaf(ETA, du, uo);
    u[idx] = un; a[idx] = softt(un, lam);
}

// ===========================================================================
extern "C" void kernel_launch(void* const* d_in, const int* in_sizes, int n_in,
                              void* d_out, int out_size, void* d_ws, size_t ws_size,
                              hipStream_t stream) {
    const float* x    = (const float*)d_in[0];
    const float* phi  = (const float*)d_in[1];
    const float* lamp = (const float*)d_in[2];
    float* a = (float*)d_out;
    char* ws = (char*)d_ws;

    // rot region (98 x 256 KB) overlays phiT (24 MB): phiT is dead once
    // lca_binit completes, before lca_persist starts.
    const size_t ROT_OFF  = 0;
    const size_t ROT_BYTES= (size_t)(STEPS - 1) * SLOT * 2;         // 25.69 MB
    const size_t PHIT_OFF = 0;                                       // overlay
    const size_t G_OFF    = ROT_OFF + ROT_BYTES;                     // 25.69 MB
    const size_t B_OFF    = G_OFF + (size_t)NEU * NEU * 2;           // +32 MB
    const size_t ARR_OFF  = B_OFF + (size_t)BATCH * NEU * 4;
    const size_t NEED     = ARR_OFF + (size_t)NBLK * 64;             // ~57.0 MB

    if (ws_size >= NEED) {
        unsigned short* phiT = (unsigned short*)(ws + PHIT_OFF);
        unsigned short* rot  = (unsigned short*)(ws + ROT_OFF);
        unsigned short* G    = (unsigned short*)(ws + G_OFF);
        float*          b    = (float*)(ws + B_OFF);
        unsigned int*   arr  = (unsigned int*)(ws + ARR_OFF);

        transp<<<dim3(NEU / 64, PIX / 64), 256, 0, stream>>>(phi, phiT);
        gemm_G<<<dim3(32, 32), 256, 0, stream>>>(phiT, G);
        lca_binit<<<256, 512, 0, stream>>>(x, phiT, b, arr);

        void* args[6];
        const unsigned short* Gc = G;
        const float* bc = b;
        const float* lc = lamp;
        args[0] = (void*)&Gc;
        args[1] = (void*)&bc;
        args[2] = (void*)&rot;
        args[3] = (void*)&a;
        args[4] = (void*)&lc;
        args[5] = (void*)&arr;
        hipLaunchCooperativeKernel((const void*)lca_persist, dim3(NBLK), dim3(TPB),
                                   args, 0, stream);
    } else {
        float* fws = (float*)d_ws;
        float* b = fws;
        float* u = fws + BATCH * NEU;
        float* s = fws + 2 * BATCH * NEU;
        lca_init_f<<<dim3(64, 8), 256, 0, stream>>>(x, phi, b, u, a);
        for (int it = 0; it < STEPS; ++it) {
            lca_s_f<<<dim3(96, 32), 256, 0, stream>>>(a, phi, s);
            lca_t_f<<<dim3(64, 4), 512, 0, stream>>>(s, phi, b, u, a, lamp);
        }
    }
}